// Round 2
// baseline (277.733 us; speedup 1.0000x reference)
//
#include <hip/hip_runtime.h>
#include <math.h>

namespace {

typedef __bf16 bf16x8 __attribute__((ext_vector_type(8)));
typedef __bf16 bf16x4 __attribute__((ext_vector_type(4)));
typedef float  f32x4  __attribute__((ext_vector_type(4)));
typedef float  f32x2  __attribute__((ext_vector_type(2)));

typedef __attribute__((address_space(1))) const char GChar;
typedef __attribute__((address_space(3))) char LChar;

constexpr int B_      = 65536;
constexpr int OBS_DIM_= 85;
constexpr int NL_     = 5;
constexpr int NT_     = 10;
constexpr int HID_    = 64;
constexpr int NACT_   = 5;
constexpr float ALPHA_= 0.01f;

__device__ __forceinline__ float leaky(float x)    { return fmaf(fminf(x, 0.0f), ALPHA_ - 1.0f, x); }
__device__ __forceinline__ float sigmoidf(float x) { return 1.0f / (1.0f + __expf(-x)); }
__device__ __forceinline__ float tanh_fast(float x){ return 1.0f - 2.0f / (__expf(2.0f * x) + 1.0f); }

// ---------------------------------------------------------------------------
// Prep (unchanged from r12): Wa = W@a, bf16 Wih/Whh (column-permuted:
// permuted row nt*16+l holds original row 4l+nt within each gate block),
// bf16 Wf1T (64x96, K = [obs(85), o5(5), zero(6)]).
// ---------------------------------------------------------------------------
__global__ void prep_kernel(const float* __restrict__ W, const float* __restrict__ a,
                            const float* __restrict__ w_ih, const float* __restrict__ w_hh,
                            const float* __restrict__ w_fc1, void* __restrict__ ws) {
  float* Wa   = (float*)ws;
  __bf16* ih  = (__bf16*)((char*)ws + 512);
  __bf16* hh  = ih + 192 * 64;
  __bf16* f1t = hh + 192 * 64;
  const int tid = blockIdx.x * 256 + threadIdx.x;
  if (blockIdx.x == 0 && threadIdx.x < 64) {
    const int i = threadIdx.x;
    float s1 = 0.0f, s2 = 0.0f;
    #pragma unroll
    for (int j = 0; j < 64; ++j) {
      float w = W[i * 64 + j];
      s1 += w * a[j];
      s2 += w * a[64 + j];
    }
    Wa[i] = s1;
    Wa[64 + i] = s2;
  }
  const int stride = gridDim.x * 256;
  for (int i = tid; i < 192 * 64; i += stride) {
    int pr = i >> 6, k = i & 63;
    int g  = pr >> 6;
    int q  = pr & 63;
    int orig = (g << 6) + ((q & 15) << 2) + (q >> 4);   // 4*l + nt
    ih[i] = (__bf16)w_ih[orig * 64 + k];
    hh[i] = (__bf16)w_hh[orig * 64 + k];
  }
  for (int i = tid; i < 64 * 96; i += stride) {
    int n = i / 96, k = i - 96 * n;
    f1t[i] = (__bf16)(k < 90 ? w_fc1[k * 64 + n] : 0.0f);
  }
}

// ======================= FUSED KERNEL =======================
// 64 rows/block, 256 threads. Phases:
//   stage: obs rows (f32, linear stride-85) -> LDS via async global_load_lds
//   front: 4 passes x 16 rows (16 lanes/row, wave-local scratch), o5 -> LDS
//   gemm : per-wave 16-row MFMA tile; A-fragments assembled from LDS f32
// LDS map (39168 B total -> 4 blocks/CU):
//   [0,21760)        s_obs f32 [64][85] (linear, matches global layout)
//   [21760,35200)    union: front {s_att f32[16][5][10] @+0 (3200),
//                                  s_h1 bf16[16][5][32] @+3200 (5120),
//                                  s_h2 f32 [16][5][16] @+8320 (5120)}
//                         | gemm A_x bf16[64][72] @+0 (9216)
//   [35200..39168)   s_wh1, s_wh2, s_colm, s_cols, s_hp, s_o5[64][5]
constexpr int SXH_ = 72;

__global__ __launch_bounds__(256, 4) void fused_kernel(
    const float* __restrict__ obs, const float* __restrict__ hidden,
    const float* __restrict__ w_in0, const float* __restrict__ b_in0,
    const float* __restrict__ w_in1, const float* __restrict__ b_in1,
    const float* __restrict__ w_in2, const float* __restrict__ b_in2,
    const float* __restrict__ w_o1, const float* __restrict__ b_o1,
    const float* __restrict__ w_o2, const float* __restrict__ b_o2,
    const float* __restrict__ w_o3, const float* __restrict__ b_o3,
    const float* __restrict__ b_fc1,
    const float* __restrict__ b_ih, const float* __restrict__ b_hh,
    const float* __restrict__ w_fc2, const float* __restrict__ b_fc2,
    const void* __restrict__ wsv,
    float* __restrict__ q_out, float* __restrict__ h_out) {

  __shared__ __align__(16) char smem[39168];
  float* s_obs = (float*)smem;
  float  (*s_att)[5][10] = (float (*)[5][10])(smem + 21760);
  __bf16 (*s_h1)[5][32]  = (__bf16 (*)[5][32])(smem + 24960);
  float  (*s_h2)[5][16]  = (float (*)[5][16])(smem + 30080);
  __bf16* A_x            = (__bf16*)(smem + 21760);
  float (*s_wh1)[12]     = (float (*)[12])(smem + 35200);
  float (*s_wh2)[12]     = (float (*)[12])(smem + 35968);
  float (*s_colm)[6]     = (float (*)[6])(smem + 36736);
  float (*s_cols)[6]     = (float (*)[6])(smem + 37120);
  float (*s_hp)[6]       = (float (*)[6])(smem + 37504);
  float* s_o5            = (float*)(smem + 37888);

  const int tid  = threadIdx.x;
  const int wv   = tid >> 6;
  const int lane = tid & 63;
  const int l16  = lane & 15;
  const int grp  = tid >> 4;               // 0..15 (row group within a pass)
  const long gr0 = (long)blockIdx.x * 64;

  const float* Wa = (const float*)wsv;
  const __bf16* Wih = (const __bf16*)((const char*)wsv + 512);
  const __bf16* Whh = Wih + 192 * 64;
  const __bf16* Wf1 = Whh + 192 * 64;

  // ---- stage: async copy 64 rows x 85 f32 (21760 B) into LDS, linear ----
  {
    const char* gbase = (const char*)(obs + gr0 * OBS_DIM_) + wv * 5440;
    char* lbase = smem + wv * 5440;
    #pragma unroll
    for (int j = 0; j < 5; ++j)
      __builtin_amdgcn_global_load_lds((const GChar*)(gbase + j * 1024 + lane * 16),
                                       (LChar*)(lbase + j * 1024 + lane * 16), 16, 0, 0);
    if (lane < 20)
      __builtin_amdgcn_global_load_lds((const GChar*)(gbase + 5120 + lane * 16),
                                       (LChar*)(lbase + 5120 + lane * 16), 16, 0, 0);
  }

  const int u0 = l16 * 4;
  const f32x4 wa1 = *(const f32x4*)&Wa[u0];
  const f32x4 wa2 = *(const f32x4*)&Wa[64 + u0];

  asm volatile("s_waitcnt vmcnt(0)" ::: "memory");
  __syncthreads();

  // ================= FRONT PHASE: 4 passes x 16 rows =================
  #pragma unroll 1
  for (int pass = 0; pass < 4; ++pass) {
    const int row = pass * 16 + grp;                 // block-local row 0..63
    const float* orow = s_obs + row * OBS_DIM_;

    f32x4 wA[8];
    f32x4 bA;
    #pragma unroll
    for (int t = 0; t < NT_; ++t) {
      if (t == 0) {
        #pragma unroll
        for (int f = 0; f < 8; ++f) wA[f] = *(const f32x4*)&w_in0[f * 64 + u0];
        bA = *(const f32x4*)&b_in0[u0];
      }
      if (t == 5) {
        #pragma unroll
        for (int f = 0; f < 8; ++f) wA[f] = *(const f32x4*)&w_in1[f * 64 + u0];
        bA = *(const f32x4*)&b_in1[u0];
      }
      if (t == 9) {
        #pragma unroll
        for (int f = 0; f < 8; ++f) wA[f] = *(const f32x4*)&w_in2[f * 64 + u0];
        bA = *(const f32x4*)&b_in2[u0];
      }
      const int ia = t * 8 + 4;
      int ib = t * 8 + 8;
      if (ib >= 80) ib = 0;
      float oa[4], ob[4];
      #pragma unroll
      for (int e = 0; e < 4; ++e) { oa[e] = orow[ia + e]; ob[e] = orow[ib + e]; }
      f32x4 z = bA;
      #pragma unroll
      for (int f = 0; f < 4; ++f) {
        z[0] += oa[f] * wA[f][0]; z[1] += oa[f] * wA[f][1];
        z[2] += oa[f] * wA[f][2]; z[3] += oa[f] * wA[f][3];
      }
      #pragma unroll
      for (int f = 4; f < 8; ++f) {
        z[0] += ob[f - 4] * wA[f][0]; z[1] += ob[f - 4] * wA[f][1];
        z[2] += ob[f - 4] * wA[f][2]; z[3] += ob[f - 4] * wA[f][3];
      }
      float h0 = leaky(z[0]), h1 = leaky(z[1]), h2 = leaky(z[2]), h3 = leaky(z[3]);
      float p1t = h0 * wa1[0] + h1 * wa1[1] + h2 * wa1[2] + h3 * wa1[3];
      float p2t = h0 * wa2[0] + h1 * wa2[1] + h2 * wa2[2] + h3 * wa2[3];
      p1t += __shfl_xor(p1t, 1, 64);  p2t += __shfl_xor(p2t, 1, 64);
      p1t += __shfl_xor(p1t, 2, 64);  p2t += __shfl_xor(p2t, 2, 64);
      p1t += __shfl_xor(p1t, 4, 64);  p2t += __shfl_xor(p2t, 4, 64);
      p1t += __shfl_xor(p1t, 8, 64);  p2t += __shfl_xor(p2t, 8, 64);
      if (l16 == 0) { s_wh1[grp][t] = p1t; s_wh2[grp][t] = p2t; }
    }

    // att1 column softmax stats (lanes 5..9)
    if (l16 >= 5 && l16 < 10) {
      const int jj = l16 - 5;
      float w1v = s_wh1[grp][NL_ + jj];
      float ev[NL_], m = -1e30f;
      #pragma unroll
      for (int k = 0; k < NL_; ++k) { ev[k] = leaky(w1v + s_wh2[grp][k]); m = fmaxf(m, ev[k]); }
      float s = 0.0f;
      #pragma unroll
      for (int k = 0; k < NL_; ++k) s += __expf(ev[k] - m);
      s_colm[grp][jj] = m;
      s_cols[grp][jj] = s;
    }

    // attention rows (lanes 0..4)
    if (l16 < NL_) {
      const int r = l16;
      const float wh1_r = s_wh1[grp][r];
      const float wh2_r = s_wh2[grp][r];
      float ev[NL_], m = -1e30f;
      #pragma unroll
      for (int j = 0; j < NL_; ++j) { ev[j] = leaky(wh1_r + s_wh2[grp][NL_ + j]); m = fmaxf(m, ev[j]); }
      float a0[NL_], s = 0.0f;
      #pragma unroll
      for (int j = 0; j < NL_; ++j) { a0[j] = __expf(ev[j] - m); s += a0[j]; }
      float inv = 1.0f / s;
      #pragma unroll
      for (int j = 0; j < NL_; ++j) s_att[grp][r][j] = a0[j] * inv;
      #pragma unroll
      for (int jj = 0; jj < NL_; ++jj) {
        float e = leaky(s_wh1[grp][NL_ + jj] + wh2_r);
        s_att[grp][r][NL_ + jj] = __expf(e - s_colm[grp][jj]) / s_cols[grp][jj];
      }
    }

    // h1: lane owns units 2*l16, 2*l16+1 (stored bf16)
    {
      f32x2 w1c[NT_];
      #pragma unroll
      for (int k = 0; k < NT_; ++k) w1c[k] = *(const f32x2*)&w_o1[k * 32 + l16 * 2];
      const f32x2 b1 = *(const f32x2*)&b_o1[l16 * 2];
      #pragma unroll
      for (int r5 = 0; r5 < NL_; ++r5) {
        float za = b1[0], zb = b1[1];
        #pragma unroll
        for (int k2 = 0; k2 < 5; ++k2) {
          f32x2 at = *(const f32x2*)&s_att[grp][r5][k2 * 2];
          za += at[0] * w1c[2 * k2][0] + at[1] * w1c[2 * k2 + 1][0];
          zb += at[0] * w1c[2 * k2][1] + at[1] * w1c[2 * k2 + 1][1];
        }
        s_h1[grp][r5][l16 * 2]     = (__bf16)leaky(za);
        s_h1[grp][r5][l16 * 2 + 1] = (__bf16)leaky(zb);
      }
    }

    // h2: lane owns unit l16
    {
      float w2c[32];
      #pragma unroll
      for (int k = 0; k < 32; ++k) w2c[k] = w_o2[k * 16 + l16];
      const float b2 = b_o2[l16];
      #pragma unroll
      for (int r5 = 0; r5 < NL_; ++r5) {
        float z = b2;
        #pragma unroll
        for (int k4 = 0; k4 < 8; ++k4) {
          bf16x4 hv = *(const bf16x4*)&s_h1[grp][r5][k4 * 4];
          z += (float)hv[0] * w2c[4 * k4] + (float)hv[1] * w2c[4 * k4 + 1]
             + (float)hv[2] * w2c[4 * k4 + 2] + (float)hv[3] * w2c[4 * k4 + 3];
        }
        s_h2[grp][r5][l16] = leaky(z);
      }
    }

    // hp + softmax -> s_o5 (lanes 0..4)
    if (l16 < NL_) {
      float z3 = b_o3[0];
      #pragma unroll
      for (int k4 = 0; k4 < 4; ++k4) {
        f32x4 hv = *(const f32x4*)&s_h2[grp][l16][k4 * 4];
        z3 += hv[0] * w_o3[4 * k4] + hv[1] * w_o3[4 * k4 + 1]
            + hv[2] * w_o3[4 * k4 + 2] + hv[3] * w_o3[4 * k4 + 3];
      }
      float hp_own = leaky(z3);
      s_hp[grp][l16] = hp_own;
      float m5 = -1e30f;
      #pragma unroll
      for (int j = 0; j < NL_; ++j) m5 = fmaxf(m5, s_hp[grp][j]);
      float ssum = 0.0f;
      #pragma unroll
      for (int j = 0; j < NL_; ++j) ssum += __expf(s_hp[grp][j] - m5);
      s_o5[row * NL_ + l16] = __expf(hp_own - m5) / ssum;
    }
  }

  __syncthreads();   // all 64 rows' o5 ready; front scratch dead -> A_x may overwrite

  // ================= GEMM PHASE: wave wv owns rows r0..r0+15 =================
  const int l    = l16;
  const int quad = lane >> 4;
  const int r0   = wv * 16;

  // hidden A-fragments direct from global
  bf16x8 ah[2];
  {
    const float* hrow_g = hidden + (gr0 + r0 + l) * HID_;
    f32x4 vha0 = *(const f32x4*)&hrow_g[quad * 8];
    f32x4 vha1 = *(const f32x4*)&hrow_g[quad * 8 + 4];
    f32x4 vhb0 = *(const f32x4*)&hrow_g[32 + quad * 8];
    f32x4 vhb1 = *(const f32x4*)&hrow_g[32 + quad * 8 + 4];
    bf16x8 t;
    t[0] = (__bf16)vha0[0]; t[1] = (__bf16)vha0[1]; t[2] = (__bf16)vha0[2]; t[3] = (__bf16)vha0[3];
    t[4] = (__bf16)vha1[0]; t[5] = (__bf16)vha1[1]; t[6] = (__bf16)vha1[2]; t[7] = (__bf16)vha1[3];
    ah[0] = t;
    t[0] = (__bf16)vhb0[0]; t[1] = (__bf16)vhb0[1]; t[2] = (__bf16)vhb0[2]; t[3] = (__bf16)vhb0[3];
    t[4] = (__bf16)vhb1[0]; t[5] = (__bf16)vhb1[1]; t[6] = (__bf16)vhb1[2]; t[7] = (__bf16)vhb1[3];
    ah[1] = t;
  }

  bf16x8 bf1[3][4];
  #pragma unroll
  for (int ks = 0; ks < 3; ++ks)
    #pragma unroll
    for (int nt = 0; nt < 4; ++nt)
      bf1[ks][nt] = *(const bf16x8*)&Wf1[(nt * 16 + l) * 96 + ks * 32 + quad * 8];

  const f32x4 zero4 = {0.0f, 0.0f, 0.0f, 0.0f};
  const float* myrow = s_obs + (r0 + l) * OBS_DIM_;
  const float* myo5  = s_o5 + (r0 + l) * NL_;

  // fc1: C[16x64] = [obs|o5|0][16x96] @ Wf1T
  f32x4 cx[4];
  #pragma unroll
  for (int nt = 0; nt < 4; ++nt) cx[nt] = zero4;
  #pragma unroll
  for (int ks = 0; ks < 3; ++ks) {
    bf16x8 af;
    if (ks < 2) {
      const int cb = ks * 32 + quad * 8;
      #pragma unroll
      for (int j = 0; j < 8; ++j) af[j] = (__bf16)myrow[cb + j];
    } else {
      if (quad < 2) {
        const int cb = 64 + quad * 8;
        #pragma unroll
        for (int j = 0; j < 8; ++j) af[j] = (__bf16)myrow[cb + j];
      } else if (quad == 2) {
        #pragma unroll
        for (int j = 0; j < 5; ++j) af[j] = (__bf16)myrow[80 + j];
        #pragma unroll
        for (int j = 5; j < 8; ++j) af[j] = (__bf16)myo5[j - 5];
      } else {
        af[0] = (__bf16)myo5[3];
        af[1] = (__bf16)myo5[4];
        #pragma unroll
        for (int j = 2; j < 8; ++j) af[j] = (__bf16)0.0f;
      }
    }
    #pragma unroll
    for (int nt = 0; nt < 4; ++nt)
      cx[nt] = __builtin_amdgcn_mfma_f32_16x16x32_bf16(af, bf1[ks][nt], cx[nt], 0, 0, 0);
  }
  #pragma unroll
  for (int nt = 0; nt < 4; ++nt) {
    float bias = b_fc1[nt * 16 + l];
    #pragma unroll
    for (int rg = 0; rg < 4; ++rg) {
      float xv = fmaxf(cx[nt][rg] + bias, 0.0f);
      A_x[(r0 + quad * 4 + rg) * SXH_ + nt * 16 + l] = (__bf16)xv;
    }
  }

  // GRU GEMMs (B-columns permuted: tile nt, lane l == orig col 4l+nt)
  bf16x8 ax[2];
  #pragma unroll
  for (int ks = 0; ks < 2; ++ks)
    ax[ks] = *(const bf16x8*)&A_x[(r0 + l) * SXH_ + ks * 32 + quad * 8];

  f32x4 crz[8], cni[4], cnh[4];
  #pragma unroll
  for (int nt = 0; nt < 8; ++nt) crz[nt] = zero4;
  #pragma unroll
  for (int nt = 0; nt < 4; ++nt) { cni[nt] = zero4; cnh[nt] = zero4; }
  #pragma unroll
  for (int nt = 0; nt < 8; ++nt) {
    #pragma unroll
    for (int ks = 0; ks < 2; ++ks) {
      bf16x8 bi = *(const bf16x8*)&Wih[(nt * 16 + l) * 64 + ks * 32 + quad * 8];
      crz[nt] = __builtin_amdgcn_mfma_f32_16x16x32_bf16(ax[ks], bi, crz[nt], 0, 0, 0);
      bf16x8 bh = *(const bf16x8*)&Whh[(nt * 16 + l) * 64 + ks * 32 + quad * 8];
      crz[nt] = __builtin_amdgcn_mfma_f32_16x16x32_bf16(ah[ks], bh, crz[nt], 0, 0, 0);
    }
  }
  #pragma unroll
  for (int nt = 0; nt < 4; ++nt) {
    #pragma unroll
    for (int ks = 0; ks < 2; ++ks) {
      bf16x8 bi = *(const bf16x8*)&Wih[(128 + nt * 16 + l) * 64 + ks * 32 + quad * 8];
      cni[nt] = __builtin_amdgcn_mfma_f32_16x16x32_bf16(ax[ks], bi, cni[nt], 0, 0, 0);
      bf16x8 bh = *(const bf16x8*)&Whh[(128 + nt * 16 + l) * 64 + ks * 32 + quad * 8];
      cnh[nt] = __builtin_amdgcn_mfma_f32_16x16x32_bf16(ah[ks], bh, cnh[nt], 0, 0, 0);
    }
  }

  // epilogue: lane l owns orig cols 4l..4l+3
  const long grow = gr0 + r0 + quad * 4;

  f32x4 br4, bz4, bin4, bhn4;
  {
    f32x4 a0 = *(const f32x4*)&b_ih[4 * l];
    f32x4 a1 = *(const f32x4*)&b_hh[4 * l];
    br4 = a0 + a1;
    a0 = *(const f32x4*)&b_ih[64 + 4 * l];
    a1 = *(const f32x4*)&b_hh[64 + 4 * l];
    bz4 = a0 + a1;
    bin4 = *(const f32x4*)&b_ih[128 + 4 * l];
    bhn4 = *(const f32x4*)&b_hh[128 + 4 * l];
  }
  f32x4 w20[5];
  #pragma unroll
  for (int j = 0; j < 5; ++j) w20[j] = *(const f32x4*)&w_fc2[20 * l + 4 * j];

  float qp[4][NACT_];
  #pragma unroll
  for (int rg = 0; rg < 4; ++rg)
    #pragma unroll
    for (int c = 0; c < NACT_; ++c) qp[rg][c] = 0.0f;

  #pragma unroll
  for (int rg = 0; rg < 4; ++rg) {
    f32x4 hold = *(const f32x4*)&hidden[(grow + rg) * HID_ + 4 * l];
    f32x4 hnew;
    #pragma unroll
    for (int t = 0; t < 4; ++t) {
      float rr = sigmoidf(crz[t][rg] + br4[t]);
      float zz = sigmoidf(crz[4 + t][rg] + bz4[t]);
      float nn = tanh_fast(cni[t][rg] + bin4[t] + rr * (cnh[t][rg] + bhn4[t]));
      float hn = (1.0f - zz) * nn + zz * hold[t];
      hnew[t] = hn;
      #pragma unroll
      for (int c = 0; c < NACT_; ++c)
        qp[rg][c] += hn * w20[(5 * t + c) >> 2][(5 * t + c) & 3];
    }
    *(f32x4*)&h_out[(grow + rg) * HID_ + 4 * l] = hnew;
  }

  #pragma unroll
  for (int m = 1; m < 16; m <<= 1) {
    #pragma unroll
    for (int rg = 0; rg < 4; ++rg)
      #pragma unroll
      for (int c = 0; c < NACT_; ++c) qp[rg][c] += __shfl_xor(qp[rg][c], m, 64);
  }
  if (l < NACT_) {
    #pragma unroll
    for (int rg = 0; rg < 4; ++rg) {
      float qv = qp[rg][0];
      if (l == 1) qv = qp[rg][1];
      if (l == 2) qv = qp[rg][2];
      if (l == 3) qv = qp[rg][3];
      if (l == 4) qv = qp[rg][4];
      q_out[(grow + rg) * NACT_ + l] = qv + b_fc2[l];
    }
  }
}

}  // namespace

extern "C" void kernel_launch(void* const* d_in, const int* in_sizes, int n_in,
                              void* d_out, int out_size, void* d_ws, size_t ws_size,
                              hipStream_t stream) {
  const float* obs    = (const float*)d_in[0];
  const float* hidden = (const float*)d_in[1];
  const float* w_in0  = (const float*)d_in[2];
  const float* b_in0  = (const float*)d_in[3];
  const float* w_in1  = (const float*)d_in[4];
  const float* b_in1  = (const float*)d_in[5];
  const float* w_in2  = (const float*)d_in[6];
  const float* b_in2  = (const float*)d_in[7];
  const float* W      = (const float*)d_in[8];
  const float* a      = (const float*)d_in[9];
  const float* w_o1   = (const float*)d_in[10];
  const float* b_o1   = (const float*)d_in[11];
  const float* w_o2   = (const float*)d_in[12];
  const float* b_o2   = (const float*)d_in[13];
  const float* w_o3   = (const float*)d_in[14];
  const float* b_o3   = (const float*)d_in[15];
  const float* w_fc1  = (const float*)d_in[16];
  const float* b_fc1  = (const float*)d_in[17];
  const float* w_ih   = (const float*)d_in[18];
  const float* w_hh   = (const float*)d_in[19];
  const float* b_ih   = (const float*)d_in[20];
  const float* b_hh   = (const float*)d_in[21];
  const float* w_fc2  = (const float*)d_in[22];
  const float* b_fc2  = (const float*)d_in[23];

  float* q_out = (float*)d_out;                  // (B,5)
  float* h_out = q_out + (long)B_ * NACT_;       // (B,64)

  prep_kernel<<<48, 256, 0, stream>>>(W, a, w_ih, w_hh, w_fc1, d_ws);
  fused_kernel<<<B_ / 64, 256, 0, stream>>>(
      obs, hidden,
      w_in0, b_in0, w_in1, b_in1, w_in2, b_in2,
      w_o1, b_o1, w_o2, b_o2, w_o3, b_o3,
      b_fc1, b_ih, b_hh, w_fc2, b_fc2,
      d_ws, q_out, h_out);
}

// Round 3
// 235.396 us; speedup vs baseline: 1.1799x; 1.1799x over previous
//
#include <hip/hip_runtime.h>
#include <math.h>

namespace {

typedef __bf16 bf16x8 __attribute__((ext_vector_type(8)));
typedef __bf16 bf16x4 __attribute__((ext_vector_type(4)));
typedef float  f32x4  __attribute__((ext_vector_type(4)));
typedef float  f32x2  __attribute__((ext_vector_type(2)));

typedef __attribute__((address_space(1))) const char GChar;
typedef __attribute__((address_space(3))) char LChar;

constexpr int B_      = 65536;
constexpr int OBS_DIM_= 85;
constexpr int NL_     = 5;
constexpr int NT_     = 10;
constexpr int HID_    = 64;
constexpr int NACT_   = 5;
constexpr float ALPHA_= 0.01f;

__device__ __forceinline__ float leaky(float x)    { return fmaf(fminf(x, 0.0f), ALPHA_ - 1.0f, x); }
__device__ __forceinline__ float sigmoidf(float x) { return 1.0f / (1.0f + __expf(-x)); }
__device__ __forceinline__ float tanh_fast(float x){ return 1.0f - 2.0f / (__expf(2.0f * x) + 1.0f); }

// ---------------------------------------------------------------------------
// Prep: Wa = W@a, bf16 Wih/Whh (column-permuted: permuted row nt*16+l holds
// original row 4l+nt within each 64-row gate block), bf16 Wf1T (64x96).
// ---------------------------------------------------------------------------
__global__ void prep_kernel(const float* __restrict__ W, const float* __restrict__ a,
                            const float* __restrict__ w_ih, const float* __restrict__ w_hh,
                            const float* __restrict__ w_fc1, void* __restrict__ ws) {
  float* Wa   = (float*)ws;
  __bf16* ih  = (__bf16*)((char*)ws + 512);
  __bf16* hh  = ih + 192 * 64;
  __bf16* f1t = hh + 192 * 64;
  const int tid = blockIdx.x * 256 + threadIdx.x;
  if (blockIdx.x == 0 && threadIdx.x < 64) {
    const int i = threadIdx.x;
    float s1 = 0.0f, s2 = 0.0f;
    #pragma unroll
    for (int j = 0; j < 64; ++j) {
      float w = W[i * 64 + j];
      s1 += w * a[j];
      s2 += w * a[64 + j];
    }
    Wa[i] = s1;
    Wa[64 + i] = s2;
  }
  const int stride = gridDim.x * 256;
  for (int i = tid; i < 192 * 64; i += stride) {
    int pr = i >> 6, k = i & 63;
    int g  = pr >> 6;
    int q  = pr & 63;
    int orig = (g << 6) + ((q & 15) << 2) + (q >> 4);   // 4*l + nt
    ih[i] = (__bf16)w_ih[orig * 64 + k];
    hh[i] = (__bf16)w_hh[orig * 64 + k];
  }
  for (int i = tid; i < 64 * 96; i += stride) {
    int n = i / 96, k = i - 96 * n;
    f1t[i] = (__bf16)(k < 90 ? w_fc1[k * 64 + n] : 0.0f);
  }
}

// ======================= FUSED KERNEL =======================
// r14: spill fix. r13's fused kernel spilled ~134 dwords/thread to scratch
// (WRITE_SIZE 152 MB vs 18 MB ideal) because the GRU section's peak register
// demand (~150) exceeded launch_bounds(256,4)'s 128-VGPR cap. Fix:
// (a) __launch_bounds__(256,3): cap 170 VGPR, 3 blocks/CU (LDS also allows 3);
// (b) gate-split GRU: compute+retire r/gh_n, then gi_n, then z -- peak live
//     accumulators 32 instead of 64, identical per-accumulator MFMA order.
constexpr int SXH_ = 72;

__global__ __launch_bounds__(256, 3) void fused_kernel(
    const float* __restrict__ obs, const float* __restrict__ hidden,
    const float* __restrict__ w_in0, const float* __restrict__ b_in0,
    const float* __restrict__ w_in1, const float* __restrict__ b_in1,
    const float* __restrict__ w_in2, const float* __restrict__ b_in2,
    const float* __restrict__ w_o1, const float* __restrict__ b_o1,
    const float* __restrict__ w_o2, const float* __restrict__ b_o2,
    const float* __restrict__ w_o3, const float* __restrict__ b_o3,
    const float* __restrict__ b_fc1,
    const float* __restrict__ b_ih, const float* __restrict__ b_hh,
    const float* __restrict__ w_fc2, const float* __restrict__ b_fc2,
    const void* __restrict__ wsv,
    float* __restrict__ q_out, float* __restrict__ h_out) {

  __shared__ __align__(16) char smem[39168];
  float* s_obs = (float*)smem;
  float  (*s_att)[5][10] = (float (*)[5][10])(smem + 21760);
  __bf16 (*s_h1)[5][32]  = (__bf16 (*)[5][32])(smem + 24960);
  float  (*s_h2)[5][16]  = (float (*)[5][16])(smem + 30080);
  __bf16* A_x            = (__bf16*)(smem + 21760);
  float (*s_wh1)[12]     = (float (*)[12])(smem + 35200);
  float (*s_wh2)[12]     = (float (*)[12])(smem + 35968);
  float (*s_colm)[6]     = (float (*)[6])(smem + 36736);
  float (*s_cols)[6]     = (float (*)[6])(smem + 37120);
  float (*s_hp)[6]       = (float (*)[6])(smem + 37504);
  float* s_o5            = (float*)(smem + 37888);

  const int tid  = threadIdx.x;
  const int wv   = tid >> 6;
  const int lane = tid & 63;
  const int l16  = lane & 15;
  const int grp  = tid >> 4;               // 0..15 (row group within a pass)
  const long gr0 = (long)blockIdx.x * 64;

  const float* Wa = (const float*)wsv;
  const __bf16* Wih = (const __bf16*)((const char*)wsv + 512);
  const __bf16* Whh = Wih + 192 * 64;
  const __bf16* Wf1 = Whh + 192 * 64;

  // ---- stage: async copy 64 rows x 85 f32 (21760 B) into LDS, linear ----
  {
    const char* gbase = (const char*)(obs + gr0 * OBS_DIM_) + wv * 5440;
    char* lbase = smem + wv * 5440;
    #pragma unroll
    for (int j = 0; j < 5; ++j)
      __builtin_amdgcn_global_load_lds((const GChar*)(gbase + j * 1024 + lane * 16),
                                       (LChar*)(lbase + j * 1024 + lane * 16), 16, 0, 0);
    if (lane < 20)
      __builtin_amdgcn_global_load_lds((const GChar*)(gbase + 5120 + lane * 16),
                                       (LChar*)(lbase + 5120 + lane * 16), 16, 0, 0);
  }

  const int u0 = l16 * 4;
  const f32x4 wa1 = *(const f32x4*)&Wa[u0];
  const f32x4 wa2 = *(const f32x4*)&Wa[64 + u0];

  asm volatile("s_waitcnt vmcnt(0)" ::: "memory");
  __syncthreads();

  // ================= FRONT PHASE: 4 passes x 16 rows =================
  #pragma unroll 1
  for (int pass = 0; pass < 4; ++pass) {
    const int row = pass * 16 + grp;                 // block-local row 0..63
    const float* orow = s_obs + row * OBS_DIM_;

    f32x4 wA[8];
    f32x4 bA;
    #pragma unroll
    for (int t = 0; t < NT_; ++t) {
      if (t == 0) {
        #pragma unroll
        for (int f = 0; f < 8; ++f) wA[f] = *(const f32x4*)&w_in0[f * 64 + u0];
        bA = *(const f32x4*)&b_in0[u0];
      }
      if (t == 5) {
        #pragma unroll
        for (int f = 0; f < 8; ++f) wA[f] = *(const f32x4*)&w_in1[f * 64 + u0];
        bA = *(const f32x4*)&b_in1[u0];
      }
      if (t == 9) {
        #pragma unroll
        for (int f = 0; f < 8; ++f) wA[f] = *(const f32x4*)&w_in2[f * 64 + u0];
        bA = *(const f32x4*)&b_in2[u0];
      }
      const int ia = t * 8 + 4;
      int ib = t * 8 + 8;
      if (ib >= 80) ib = 0;
      float oa[4], ob[4];
      #pragma unroll
      for (int e = 0; e < 4; ++e) { oa[e] = orow[ia + e]; ob[e] = orow[ib + e]; }
      f32x4 z = bA;
      #pragma unroll
      for (int f = 0; f < 4; ++f) {
        z[0] += oa[f] * wA[f][0]; z[1] += oa[f] * wA[f][1];
        z[2] += oa[f] * wA[f][2]; z[3] += oa[f] * wA[f][3];
      }
      #pragma unroll
      for (int f = 4; f < 8; ++f) {
        z[0] += ob[f - 4] * wA[f][0]; z[1] += ob[f - 4] * wA[f][1];
        z[2] += ob[f - 4] * wA[f][2]; z[3] += ob[f - 4] * wA[f][3];
      }
      float h0 = leaky(z[0]), h1 = leaky(z[1]), h2 = leaky(z[2]), h3 = leaky(z[3]);
      float p1t = h0 * wa1[0] + h1 * wa1[1] + h2 * wa1[2] + h3 * wa1[3];
      float p2t = h0 * wa2[0] + h1 * wa2[1] + h2 * wa2[2] + h3 * wa2[3];
      p1t += __shfl_xor(p1t, 1, 64);  p2t += __shfl_xor(p2t, 1, 64);
      p1t += __shfl_xor(p1t, 2, 64);  p2t += __shfl_xor(p2t, 2, 64);
      p1t += __shfl_xor(p1t, 4, 64);  p2t += __shfl_xor(p2t, 4, 64);
      p1t += __shfl_xor(p1t, 8, 64);  p2t += __shfl_xor(p2t, 8, 64);
      if (l16 == 0) { s_wh1[grp][t] = p1t; s_wh2[grp][t] = p2t; }
    }

    // att1 column softmax stats (lanes 5..9)
    if (l16 >= 5 && l16 < 10) {
      const int jj = l16 - 5;
      float w1v = s_wh1[grp][NL_ + jj];
      float ev[NL_], m = -1e30f;
      #pragma unroll
      for (int k = 0; k < NL_; ++k) { ev[k] = leaky(w1v + s_wh2[grp][k]); m = fmaxf(m, ev[k]); }
      float s = 0.0f;
      #pragma unroll
      for (int k = 0; k < NL_; ++k) s += __expf(ev[k] - m);
      s_colm[grp][jj] = m;
      s_cols[grp][jj] = s;
    }

    // attention rows (lanes 0..4)
    if (l16 < NL_) {
      const int r = l16;
      const float wh1_r = s_wh1[grp][r];
      const float wh2_r = s_wh2[grp][r];
      float ev[NL_], m = -1e30f;
      #pragma unroll
      for (int j = 0; j < NL_; ++j) { ev[j] = leaky(wh1_r + s_wh2[grp][NL_ + j]); m = fmaxf(m, ev[j]); }
      float a0[NL_], s = 0.0f;
      #pragma unroll
      for (int j = 0; j < NL_; ++j) { a0[j] = __expf(ev[j] - m); s += a0[j]; }
      float inv = 1.0f / s;
      #pragma unroll
      for (int j = 0; j < NL_; ++j) s_att[grp][r][j] = a0[j] * inv;
      #pragma unroll
      for (int jj = 0; jj < NL_; ++jj) {
        float e = leaky(s_wh1[grp][NL_ + jj] + wh2_r);
        s_att[grp][r][NL_ + jj] = __expf(e - s_colm[grp][jj]) / s_cols[grp][jj];
      }
    }

    // h1: lane owns units 2*l16, 2*l16+1 (stored bf16)
    {
      f32x2 w1c[NT_];
      #pragma unroll
      for (int k = 0; k < NT_; ++k) w1c[k] = *(const f32x2*)&w_o1[k * 32 + l16 * 2];
      const f32x2 b1 = *(const f32x2*)&b_o1[l16 * 2];
      #pragma unroll
      for (int r5 = 0; r5 < NL_; ++r5) {
        float za = b1[0], zb = b1[1];
        #pragma unroll
        for (int k2 = 0; k2 < 5; ++k2) {
          f32x2 at = *(const f32x2*)&s_att[grp][r5][k2 * 2];
          za += at[0] * w1c[2 * k2][0] + at[1] * w1c[2 * k2 + 1][0];
          zb += at[0] * w1c[2 * k2][1] + at[1] * w1c[2 * k2 + 1][1];
        }
        s_h1[grp][r5][l16 * 2]     = (__bf16)leaky(za);
        s_h1[grp][r5][l16 * 2 + 1] = (__bf16)leaky(zb);
      }
    }

    // h2: lane owns unit l16
    {
      float w2c[32];
      #pragma unroll
      for (int k = 0; k < 32; ++k) w2c[k] = w_o2[k * 16 + l16];
      const float b2 = b_o2[l16];
      #pragma unroll
      for (int r5 = 0; r5 < NL_; ++r5) {
        float z = b2;
        #pragma unroll
        for (int k4 = 0; k4 < 8; ++k4) {
          bf16x4 hv = *(const bf16x4*)&s_h1[grp][r5][k4 * 4];
          z += (float)hv[0] * w2c[4 * k4] + (float)hv[1] * w2c[4 * k4 + 1]
             + (float)hv[2] * w2c[4 * k4 + 2] + (float)hv[3] * w2c[4 * k4 + 3];
        }
        s_h2[grp][r5][l16] = leaky(z);
      }
    }

    // hp + softmax -> s_o5 (lanes 0..4)
    if (l16 < NL_) {
      float z3 = b_o3[0];
      #pragma unroll
      for (int k4 = 0; k4 < 4; ++k4) {
        f32x4 hv = *(const f32x4*)&s_h2[grp][l16][k4 * 4];
        z3 += hv[0] * w_o3[4 * k4] + hv[1] * w_o3[4 * k4 + 1]
            + hv[2] * w_o3[4 * k4 + 2] + hv[3] * w_o3[4 * k4 + 3];
      }
      float hp_own = leaky(z3);
      s_hp[grp][l16] = hp_own;
      float m5 = -1e30f;
      #pragma unroll
      for (int j = 0; j < NL_; ++j) m5 = fmaxf(m5, s_hp[grp][j]);
      float ssum = 0.0f;
      #pragma unroll
      for (int j = 0; j < NL_; ++j) ssum += __expf(s_hp[grp][j] - m5);
      s_o5[row * NL_ + l16] = __expf(hp_own - m5) / ssum;
    }
  }

  __syncthreads();   // all o5 ready; front scratch dead -> A_x may overwrite

  // ================= GEMM PHASE: wave wv owns rows r0..r0+15 =================
  const int l    = l16;
  const int quad = lane >> 4;
  const int r0   = wv * 16;

  // hidden A-fragments direct from global
  bf16x8 ah[2];
  {
    const float* hrow_g = hidden + (gr0 + r0 + l) * HID_;
    f32x4 vha0 = *(const f32x4*)&hrow_g[quad * 8];
    f32x4 vha1 = *(const f32x4*)&hrow_g[quad * 8 + 4];
    f32x4 vhb0 = *(const f32x4*)&hrow_g[32 + quad * 8];
    f32x4 vhb1 = *(const f32x4*)&hrow_g[32 + quad * 8 + 4];
    bf16x8 t;
    t[0] = (__bf16)vha0[0]; t[1] = (__bf16)vha0[1]; t[2] = (__bf16)vha0[2]; t[3] = (__bf16)vha0[3];
    t[4] = (__bf16)vha1[0]; t[5] = (__bf16)vha1[1]; t[6] = (__bf16)vha1[2]; t[7] = (__bf16)vha1[3];
    ah[0] = t;
    t[0] = (__bf16)vhb0[0]; t[1] = (__bf16)vhb0[1]; t[2] = (__bf16)vhb0[2]; t[3] = (__bf16)vhb0[3];
    t[4] = (__bf16)vhb1[0]; t[5] = (__bf16)vhb1[1]; t[6] = (__bf16)vhb1[2]; t[7] = (__bf16)vhb1[3];
    ah[1] = t;
  }

  const f32x4 zero4 = {0.0f, 0.0f, 0.0f, 0.0f};
  const float* myrow = s_obs + (r0 + l) * OBS_DIM_;
  const float* myo5  = s_o5 + (r0 + l) * NL_;

  // fc1: C[16x64] = [obs|o5|0][16x96] @ Wf1T
  f32x4 cx[4];
  #pragma unroll
  for (int nt = 0; nt < 4; ++nt) cx[nt] = zero4;
  #pragma unroll
  for (int ks = 0; ks < 3; ++ks) {
    bf16x8 af;
    if (ks < 2) {
      const int cb = ks * 32 + quad * 8;
      #pragma unroll
      for (int j = 0; j < 8; ++j) af[j] = (__bf16)myrow[cb + j];
    } else {
      if (quad < 2) {
        const int cb = 64 + quad * 8;
        #pragma unroll
        for (int j = 0; j < 8; ++j) af[j] = (__bf16)myrow[cb + j];
      } else if (quad == 2) {
        #pragma unroll
        for (int j = 0; j < 5; ++j) af[j] = (__bf16)myrow[80 + j];
        #pragma unroll
        for (int j = 5; j < 8; ++j) af[j] = (__bf16)myo5[j - 5];
      } else {
        af[0] = (__bf16)myo5[3];
        af[1] = (__bf16)myo5[4];
        #pragma unroll
        for (int j = 2; j < 8; ++j) af[j] = (__bf16)0.0f;
      }
    }
    #pragma unroll
    for (int nt = 0; nt < 4; ++nt) {
      bf16x8 bf = *(const bf16x8*)&Wf1[(nt * 16 + l) * 96 + ks * 32 + quad * 8];
      cx[nt] = __builtin_amdgcn_mfma_f32_16x16x32_bf16(af, bf, cx[nt], 0, 0, 0);
    }
  }
  #pragma unroll
  for (int nt = 0; nt < 4; ++nt) {
    float bias = b_fc1[nt * 16 + l];
    #pragma unroll
    for (int rg = 0; rg < 4; ++rg) {
      float xv = fmaxf(cx[nt][rg] + bias, 0.0f);
      A_x[(r0 + quad * 4 + rg) * SXH_ + nt * 16 + l] = (__bf16)xv;
    }
  }

  // GRU GEMMs, gate-split (B-columns permuted: tile nt, lane l == orig col 4l+nt)
  bf16x8 ax[2];
  #pragma unroll
  for (int ks = 0; ks < 2; ++ks)
    ax[ks] = *(const bf16x8*)&A_x[(r0 + l) * SXH_ + ks * 32 + quad * 8];

  // ---- phase A: r-gates (gi_r+gh_r) and gh_n; retire into rn ----
  f32x4 cr[4], ch[4];
  #pragma unroll
  for (int nt = 0; nt < 4; ++nt) { cr[nt] = zero4; ch[nt] = zero4; }
  #pragma unroll
  for (int nt = 0; nt < 4; ++nt) {
    #pragma unroll
    for (int ks = 0; ks < 2; ++ks) {
      bf16x8 bi = *(const bf16x8*)&Wih[(nt * 16 + l) * 64 + ks * 32 + quad * 8];
      cr[nt] = __builtin_amdgcn_mfma_f32_16x16x32_bf16(ax[ks], bi, cr[nt], 0, 0, 0);
      bf16x8 bh = *(const bf16x8*)&Whh[(nt * 16 + l) * 64 + ks * 32 + quad * 8];
      cr[nt] = __builtin_amdgcn_mfma_f32_16x16x32_bf16(ah[ks], bh, cr[nt], 0, 0, 0);
    }
    #pragma unroll
    for (int ks = 0; ks < 2; ++ks) {
      bf16x8 bh = *(const bf16x8*)&Whh[(128 + nt * 16 + l) * 64 + ks * 32 + quad * 8];
      ch[nt] = __builtin_amdgcn_mfma_f32_16x16x32_bf16(ah[ks], bh, ch[nt], 0, 0, 0);
    }
  }
  f32x4 rn[4];
  {
    f32x4 a0 = *(const f32x4*)&b_ih[4 * l];
    f32x4 a1 = *(const f32x4*)&b_hh[4 * l];
    f32x4 br4 = a0 + a1;
    f32x4 bhn4 = *(const f32x4*)&b_hh[128 + 4 * l];
    #pragma unroll
    for (int nt = 0; nt < 4; ++nt)
      #pragma unroll
      for (int rg = 0; rg < 4; ++rg) {
        float rr = sigmoidf(cr[nt][rg] + br4[nt]);
        rn[nt][rg] = rr * (ch[nt][rg] + bhn4[nt]);
      }
  }

  // ---- phase B: gi_n; retire into nn ----
  f32x4 cn[4];
  #pragma unroll
  for (int nt = 0; nt < 4; ++nt) cn[nt] = zero4;
  #pragma unroll
  for (int nt = 0; nt < 4; ++nt)
    #pragma unroll
    for (int ks = 0; ks < 2; ++ks) {
      bf16x8 bi = *(const bf16x8*)&Wih[(128 + nt * 16 + l) * 64 + ks * 32 + quad * 8];
      cn[nt] = __builtin_amdgcn_mfma_f32_16x16x32_bf16(ax[ks], bi, cn[nt], 0, 0, 0);
    }
  f32x4 nn[4];
  {
    f32x4 bin4 = *(const f32x4*)&b_ih[128 + 4 * l];
    #pragma unroll
    for (int nt = 0; nt < 4; ++nt)
      #pragma unroll
      for (int rg = 0; rg < 4; ++rg)
        nn[nt][rg] = tanh_fast(cn[nt][rg] + bin4[nt] + rn[nt][rg]);
  }

  // ---- phase C: z-gates, then h / q ----
  f32x4 cz[4];
  #pragma unroll
  for (int nt = 0; nt < 4; ++nt) cz[nt] = zero4;
  #pragma unroll
  for (int nt = 0; nt < 4; ++nt)
    #pragma unroll
    for (int ks = 0; ks < 2; ++ks) {
      bf16x8 bi = *(const bf16x8*)&Wih[(64 + nt * 16 + l) * 64 + ks * 32 + quad * 8];
      cz[nt] = __builtin_amdgcn_mfma_f32_16x16x32_bf16(ax[ks], bi, cz[nt], 0, 0, 0);
      bf16x8 bh = *(const bf16x8*)&Whh[(64 + nt * 16 + l) * 64 + ks * 32 + quad * 8];
      cz[nt] = __builtin_amdgcn_mfma_f32_16x16x32_bf16(ah[ks], bh, cz[nt], 0, 0, 0);
    }

  const long grow = gr0 + r0 + quad * 4;
  f32x4 bz4;
  {
    f32x4 a0 = *(const f32x4*)&b_ih[64 + 4 * l];
    f32x4 a1 = *(const f32x4*)&b_hh[64 + 4 * l];
    bz4 = a0 + a1;
  }
  f32x4 w20[5];
  #pragma unroll
  for (int j = 0; j < 5; ++j) w20[j] = *(const f32x4*)&w_fc2[20 * l + 4 * j];

  float qp[4][NACT_];
  #pragma unroll
  for (int rg = 0; rg < 4; ++rg)
    #pragma unroll
    for (int c = 0; c < NACT_; ++c) qp[rg][c] = 0.0f;

  #pragma unroll
  for (int rg = 0; rg < 4; ++rg) {
    f32x4 hold = *(const f32x4*)&hidden[(grow + rg) * HID_ + 4 * l];
    f32x4 hnew;
    #pragma unroll
    for (int t = 0; t < 4; ++t) {
      float zz = sigmoidf(cz[t][rg] + bz4[t]);
      float hn = (1.0f - zz) * nn[t][rg] + zz * hold[t];
      hnew[t] = hn;
      #pragma unroll
      for (int c = 0; c < NACT_; ++c)
        qp[rg][c] += hn * w20[(5 * t + c) >> 2][(5 * t + c) & 3];
    }
    *(f32x4*)&h_out[(grow + rg) * HID_ + 4 * l] = hnew;
  }

  #pragma unroll
  for (int m = 1; m < 16; m <<= 1) {
    #pragma unroll
    for (int rg = 0; rg < 4; ++rg)
      #pragma unroll
      for (int c = 0; c < NACT_; ++c) qp[rg][c] += __shfl_xor(qp[rg][c], m, 64);
  }
  if (l < NACT_) {
    #pragma unroll
    for (int rg = 0; rg < 4; ++rg) {
      float qv = qp[rg][0];
      if (l == 1) qv = qp[rg][1];
      if (l == 2) qv = qp[rg][2];
      if (l == 3) qv = qp[rg][3];
      if (l == 4) qv = qp[rg][4];
      q_out[(grow + rg) * NACT_ + l] = qv + b_fc2[l];
    }
  }
}

}  // namespace

extern "C" void kernel_launch(void* const* d_in, const int* in_sizes, int n_in,
                              void* d_out, int out_size, void* d_ws, size_t ws_size,
                              hipStream_t stream) {
  const float* obs    = (const float*)d_in[0];
  const float* hidden = (const float*)d_in[1];
  const float* w_in0  = (const float*)d_in[2];
  const float* b_in0  = (const float*)d_in[3];
  const float* w_in1  = (const float*)d_in[4];
  const float* b_in1  = (const float*)d_in[5];
  const float* w_in2  = (const float*)d_in[6];
  const float* b_in2  = (const float*)d_in[7];
  const float* W      = (const float*)d_in[8];
  const float* a      = (const float*)d_in[9];
  const float* w_o1   = (const float*)d_in[10];
  const float* b_o1   = (const float*)d_in[11];
  const float* w_o2   = (const float*)d_in[12];
  const float* b_o2   = (const float*)d_in[13];
  const float* w_o3   = (const float*)d_in[14];
  const float* b_o3   = (const float*)d_in[15];
  const float* w_fc1  = (const float*)d_in[16];
  const float* b_fc1  = (const float*)d_in[17];
  const float* w_ih   = (const float*)d_in[18];
  const float* w_hh   = (const float*)d_in[19];
  const float* b_ih   = (const float*)d_in[20];
  const float* b_hh   = (const float*)d_in[21];
  const float* w_fc2  = (const float*)d_in[22];
  const float* b_fc2  = (const float*)d_in[23];

  float* q_out = (float*)d_out;                  // (B,5)
  float* h_out = q_out + (long)B_ * NACT_;       // (B,64)

  prep_kernel<<<48, 256, 0, stream>>>(W, a, w_ih, w_hh, w_fc1, d_ws);
  fused_kernel<<<B_ / 64, 256, 0, stream>>>(
      obs, hidden,
      w_in0, b_in0, w_in1, b_in1, w_in2, b_in2,
      w_o1, b_o1, w_o2, b_o2, w_o3, b_o3,
      b_fc1, b_ih, b_hh, w_fc2, b_fc2,
      d_ws, q_out, h_out);
}

// Round 4
// 198.327 us; speedup vs baseline: 1.4004x; 1.1869x over previous
//
#include <hip/hip_runtime.h>
#include <math.h>

namespace {

typedef __bf16 bf16x8 __attribute__((ext_vector_type(8)));
typedef __bf16 bf16x4 __attribute__((ext_vector_type(4)));
typedef float  f32x4  __attribute__((ext_vector_type(4)));
typedef float  f32x2  __attribute__((ext_vector_type(2)));

typedef __attribute__((address_space(1))) const char GChar;
typedef __attribute__((address_space(3))) char LChar;

constexpr int B_      = 65536;
constexpr int OBS_DIM_= 85;
constexpr int NL_     = 5;
constexpr int NT_     = 10;
constexpr int HID_    = 64;
constexpr int NACT_   = 5;
constexpr float ALPHA_= 0.01f;

__device__ __forceinline__ float leaky(float x)    { return fmaf(fminf(x, 0.0f), ALPHA_ - 1.0f, x); }
__device__ __forceinline__ float sigmoidf(float x) { return 1.0f / (1.0f + __expf(-x)); }
__device__ __forceinline__ float tanh_fast(float x){ return 1.0f - 2.0f / (__expf(2.0f * x) + 1.0f); }

// ---------------------------------------------------------------------------
// Prep: Wa = W@a, bf16 Wih/Whh (column-permuted: permuted row nt*16+l holds
// original row 4l+nt within each 64-row gate block), bf16 Wf1T (64x96).
// ---------------------------------------------------------------------------
__global__ void prep_kernel(const float* __restrict__ W, const float* __restrict__ a,
                            const float* __restrict__ w_ih, const float* __restrict__ w_hh,
                            const float* __restrict__ w_fc1, void* __restrict__ ws) {
  float* Wa   = (float*)ws;
  __bf16* ih  = (__bf16*)((char*)ws + 512);
  __bf16* hh  = ih + 192 * 64;
  __bf16* f1t = hh + 192 * 64;
  const int tid = blockIdx.x * 256 + threadIdx.x;
  if (blockIdx.x == 0 && threadIdx.x < 64) {
    const int i = threadIdx.x;
    float s1 = 0.0f, s2 = 0.0f;
    #pragma unroll
    for (int j = 0; j < 64; ++j) {
      float w = W[i * 64 + j];
      s1 += w * a[j];
      s2 += w * a[64 + j];
    }
    Wa[i] = s1;
    Wa[64 + i] = s2;
  }
  const int stride = gridDim.x * 256;
  for (int i = tid; i < 192 * 64; i += stride) {
    int pr = i >> 6, k = i & 63;
    int g  = pr >> 6;
    int q  = pr & 63;
    int orig = (g << 6) + ((q & 15) << 2) + (q >> 4);   // 4*l + nt
    ih[i] = (__bf16)w_ih[orig * 64 + k];
    hh[i] = (__bf16)w_hh[orig * 64 + k];
  }
  for (int i = tid; i < 64 * 96; i += stride) {
    int n = i / 96, k = i - 96 * n;
    f1t[i] = (__bf16)(k < 90 ? w_fc1[k * 64 + n] : 0.0f);
  }
}

// ======================= FUSED KERNEL =======================
// r15: spill kill, part 2. r14's (256,3) still spilled ~63 dwords/thread
// (WRITE 84 MB vs 18 ideal) -- arch(84) + accum VGPRs exceeded the 170 cap,
// while MEASURED occupancy was only 23% (~7.5 waves/CU). So the 170-cap paid
// spill cost without delivering occupancy. Fix: __launch_bounds__(256,2)
// (256-reg unified budget, guaranteed 8 waves/CU == what we measured anyway)
// + epilogue restructured per-rg (qp[4][5] -> qp5[5], reduce+store inside
// the rg loop; identical FLOP order, -15 regs peak pressure).
constexpr int SXH_ = 72;

__global__ __launch_bounds__(256, 2) void fused_kernel(
    const float* __restrict__ obs, const float* __restrict__ hidden,
    const float* __restrict__ w_in0, const float* __restrict__ b_in0,
    const float* __restrict__ w_in1, const float* __restrict__ b_in1,
    const float* __restrict__ w_in2, const float* __restrict__ b_in2,
    const float* __restrict__ w_o1, const float* __restrict__ b_o1,
    const float* __restrict__ w_o2, const float* __restrict__ b_o2,
    const float* __restrict__ w_o3, const float* __restrict__ b_o3,
    const float* __restrict__ b_fc1,
    const float* __restrict__ b_ih, const float* __restrict__ b_hh,
    const float* __restrict__ w_fc2, const float* __restrict__ b_fc2,
    const void* __restrict__ wsv,
    float* __restrict__ q_out, float* __restrict__ h_out) {

  __shared__ __align__(16) char smem[39168];
  float* s_obs = (float*)smem;
  float  (*s_att)[5][10] = (float (*)[5][10])(smem + 21760);
  __bf16 (*s_h1)[5][32]  = (__bf16 (*)[5][32])(smem + 24960);
  float  (*s_h2)[5][16]  = (float (*)[5][16])(smem + 30080);
  __bf16* A_x            = (__bf16*)(smem + 21760);
  float (*s_wh1)[12]     = (float (*)[12])(smem + 35200);
  float (*s_wh2)[12]     = (float (*)[12])(smem + 35968);
  float (*s_colm)[6]     = (float (*)[6])(smem + 36736);
  float (*s_cols)[6]     = (float (*)[6])(smem + 37120);
  float (*s_hp)[6]       = (float (*)[6])(smem + 37504);
  float* s_o5            = (float*)(smem + 37888);

  const int tid  = threadIdx.x;
  const int wv   = tid >> 6;
  const int lane = tid & 63;
  const int l16  = lane & 15;
  const int grp  = tid >> 4;               // 0..15 (row group within a pass)
  const long gr0 = (long)blockIdx.x * 64;

  const float* Wa = (const float*)wsv;
  const __bf16* Wih = (const __bf16*)((const char*)wsv + 512);
  const __bf16* Whh = Wih + 192 * 64;
  const __bf16* Wf1 = Whh + 192 * 64;

  // ---- stage: async copy 64 rows x 85 f32 (21760 B) into LDS, linear ----
  {
    const char* gbase = (const char*)(obs + gr0 * OBS_DIM_) + wv * 5440;
    char* lbase = smem + wv * 5440;
    #pragma unroll
    for (int j = 0; j < 5; ++j)
      __builtin_amdgcn_global_load_lds((const GChar*)(gbase + j * 1024 + lane * 16),
                                       (LChar*)(lbase + j * 1024 + lane * 16), 16, 0, 0);
    if (lane < 20)
      __builtin_amdgcn_global_load_lds((const GChar*)(gbase + 5120 + lane * 16),
                                       (LChar*)(lbase + 5120 + lane * 16), 16, 0, 0);
  }

  const int u0 = l16 * 4;
  const f32x4 wa1 = *(const f32x4*)&Wa[u0];
  const f32x4 wa2 = *(const f32x4*)&Wa[64 + u0];

  asm volatile("s_waitcnt vmcnt(0)" ::: "memory");
  __syncthreads();

  // ================= FRONT PHASE: 4 passes x 16 rows =================
  #pragma unroll 1
  for (int pass = 0; pass < 4; ++pass) {
    const int row = pass * 16 + grp;                 // block-local row 0..63
    const float* orow = s_obs + row * OBS_DIM_;

    f32x4 wA[8];
    f32x4 bA;
    #pragma unroll
    for (int t = 0; t < NT_; ++t) {
      if (t == 0) {
        #pragma unroll
        for (int f = 0; f < 8; ++f) wA[f] = *(const f32x4*)&w_in0[f * 64 + u0];
        bA = *(const f32x4*)&b_in0[u0];
      }
      if (t == 5) {
        #pragma unroll
        for (int f = 0; f < 8; ++f) wA[f] = *(const f32x4*)&w_in1[f * 64 + u0];
        bA = *(const f32x4*)&b_in1[u0];
      }
      if (t == 9) {
        #pragma unroll
        for (int f = 0; f < 8; ++f) wA[f] = *(const f32x4*)&w_in2[f * 64 + u0];
        bA = *(const f32x4*)&b_in2[u0];
      }
      const int ia = t * 8 + 4;
      int ib = t * 8 + 8;
      if (ib >= 80) ib = 0;
      float oa[4], ob[4];
      #pragma unroll
      for (int e = 0; e < 4; ++e) { oa[e] = orow[ia + e]; ob[e] = orow[ib + e]; }
      f32x4 z = bA;
      #pragma unroll
      for (int f = 0; f < 4; ++f) {
        z[0] += oa[f] * wA[f][0]; z[1] += oa[f] * wA[f][1];
        z[2] += oa[f] * wA[f][2]; z[3] += oa[f] * wA[f][3];
      }
      #pragma unroll
      for (int f = 4; f < 8; ++f) {
        z[0] += ob[f - 4] * wA[f][0]; z[1] += ob[f - 4] * wA[f][1];
        z[2] += ob[f - 4] * wA[f][2]; z[3] += ob[f - 4] * wA[f][3];
      }
      float h0 = leaky(z[0]), h1 = leaky(z[1]), h2 = leaky(z[2]), h3 = leaky(z[3]);
      float p1t = h0 * wa1[0] + h1 * wa1[1] + h2 * wa1[2] + h3 * wa1[3];
      float p2t = h0 * wa2[0] + h1 * wa2[1] + h2 * wa2[2] + h3 * wa2[3];
      p1t += __shfl_xor(p1t, 1, 64);  p2t += __shfl_xor(p2t, 1, 64);
      p1t += __shfl_xor(p1t, 2, 64);  p2t += __shfl_xor(p2t, 2, 64);
      p1t += __shfl_xor(p1t, 4, 64);  p2t += __shfl_xor(p2t, 4, 64);
      p1t += __shfl_xor(p1t, 8, 64);  p2t += __shfl_xor(p2t, 8, 64);
      if (l16 == 0) { s_wh1[grp][t] = p1t; s_wh2[grp][t] = p2t; }
    }

    // att1 column softmax stats (lanes 5..9)
    if (l16 >= 5 && l16 < 10) {
      const int jj = l16 - 5;
      float w1v = s_wh1[grp][NL_ + jj];
      float ev[NL_], m = -1e30f;
      #pragma unroll
      for (int k = 0; k < NL_; ++k) { ev[k] = leaky(w1v + s_wh2[grp][k]); m = fmaxf(m, ev[k]); }
      float s = 0.0f;
      #pragma unroll
      for (int k = 0; k < NL_; ++k) s += __expf(ev[k] - m);
      s_colm[grp][jj] = m;
      s_cols[grp][jj] = s;
    }

    // attention rows (lanes 0..4)
    if (l16 < NL_) {
      const int r = l16;
      const float wh1_r = s_wh1[grp][r];
      const float wh2_r = s_wh2[grp][r];
      float ev[NL_], m = -1e30f;
      #pragma unroll
      for (int j = 0; j < NL_; ++j) { ev[j] = leaky(wh1_r + s_wh2[grp][NL_ + j]); m = fmaxf(m, ev[j]); }
      float a0[NL_], s = 0.0f;
      #pragma unroll
      for (int j = 0; j < NL_; ++j) { a0[j] = __expf(ev[j] - m); s += a0[j]; }
      float inv = 1.0f / s;
      #pragma unroll
      for (int j = 0; j < NL_; ++j) s_att[grp][r][j] = a0[j] * inv;
      #pragma unroll
      for (int jj = 0; jj < NL_; ++jj) {
        float e = leaky(s_wh1[grp][NL_ + jj] + wh2_r);
        s_att[grp][r][NL_ + jj] = __expf(e - s_colm[grp][jj]) / s_cols[grp][jj];
      }
    }

    // h1: lane owns units 2*l16, 2*l16+1 (stored bf16)
    {
      f32x2 w1c[NT_];
      #pragma unroll
      for (int k = 0; k < NT_; ++k) w1c[k] = *(const f32x2*)&w_o1[k * 32 + l16 * 2];
      const f32x2 b1 = *(const f32x2*)&b_o1[l16 * 2];
      #pragma unroll
      for (int r5 = 0; r5 < NL_; ++r5) {
        float za = b1[0], zb = b1[1];
        #pragma unroll
        for (int k2 = 0; k2 < 5; ++k2) {
          f32x2 at = *(const f32x2*)&s_att[grp][r5][k2 * 2];
          za += at[0] * w1c[2 * k2][0] + at[1] * w1c[2 * k2 + 1][0];
          zb += at[0] * w1c[2 * k2][1] + at[1] * w1c[2 * k2 + 1][1];
        }
        s_h1[grp][r5][l16 * 2]     = (__bf16)leaky(za);
        s_h1[grp][r5][l16 * 2 + 1] = (__bf16)leaky(zb);
      }
    }

    // h2: lane owns unit l16
    {
      float w2c[32];
      #pragma unroll
      for (int k = 0; k < 32; ++k) w2c[k] = w_o2[k * 16 + l16];
      const float b2 = b_o2[l16];
      #pragma unroll
      for (int r5 = 0; r5 < NL_; ++r5) {
        float z = b2;
        #pragma unroll
        for (int k4 = 0; k4 < 8; ++k4) {
          bf16x4 hv = *(const bf16x4*)&s_h1[grp][r5][k4 * 4];
          z += (float)hv[0] * w2c[4 * k4] + (float)hv[1] * w2c[4 * k4 + 1]
             + (float)hv[2] * w2c[4 * k4 + 2] + (float)hv[3] * w2c[4 * k4 + 3];
        }
        s_h2[grp][r5][l16] = leaky(z);
      }
    }

    // hp + softmax -> s_o5 (lanes 0..4)
    if (l16 < NL_) {
      float z3 = b_o3[0];
      #pragma unroll
      for (int k4 = 0; k4 < 4; ++k4) {
        f32x4 hv = *(const f32x4*)&s_h2[grp][l16][k4 * 4];
        z3 += hv[0] * w_o3[4 * k4] + hv[1] * w_o3[4 * k4 + 1]
            + hv[2] * w_o3[4 * k4 + 2] + hv[3] * w_o3[4 * k4 + 3];
      }
      float hp_own = leaky(z3);
      s_hp[grp][l16] = hp_own;
      float m5 = -1e30f;
      #pragma unroll
      for (int j = 0; j < NL_; ++j) m5 = fmaxf(m5, s_hp[grp][j]);
      float ssum = 0.0f;
      #pragma unroll
      for (int j = 0; j < NL_; ++j) ssum += __expf(s_hp[grp][j] - m5);
      s_o5[row * NL_ + l16] = __expf(hp_own - m5) / ssum;
    }
  }

  __syncthreads();   // all o5 ready; front scratch dead -> A_x may overwrite

  // ================= GEMM PHASE: wave wv owns rows r0..r0+15 =================
  const int l    = l16;
  const int quad = lane >> 4;
  const int r0   = wv * 16;

  // hidden A-fragments direct from global
  bf16x8 ah[2];
  {
    const float* hrow_g = hidden + (gr0 + r0 + l) * HID_;
    f32x4 vha0 = *(const f32x4*)&hrow_g[quad * 8];
    f32x4 vha1 = *(const f32x4*)&hrow_g[quad * 8 + 4];
    f32x4 vhb0 = *(const f32x4*)&hrow_g[32 + quad * 8];
    f32x4 vhb1 = *(const f32x4*)&hrow_g[32 + quad * 8 + 4];
    bf16x8 t;
    t[0] = (__bf16)vha0[0]; t[1] = (__bf16)vha0[1]; t[2] = (__bf16)vha0[2]; t[3] = (__bf16)vha0[3];
    t[4] = (__bf16)vha1[0]; t[5] = (__bf16)vha1[1]; t[6] = (__bf16)vha1[2]; t[7] = (__bf16)vha1[3];
    ah[0] = t;
    t[0] = (__bf16)vhb0[0]; t[1] = (__bf16)vhb0[1]; t[2] = (__bf16)vhb0[2]; t[3] = (__bf16)vhb0[3];
    t[4] = (__bf16)vhb1[0]; t[5] = (__bf16)vhb1[1]; t[6] = (__bf16)vhb1[2]; t[7] = (__bf16)vhb1[3];
    ah[1] = t;
  }

  const f32x4 zero4 = {0.0f, 0.0f, 0.0f, 0.0f};
  const float* myrow = s_obs + (r0 + l) * OBS_DIM_;
  const float* myo5  = s_o5 + (r0 + l) * NL_;

  // fc1: C[16x64] = [obs|o5|0][16x96] @ Wf1T
  f32x4 cx[4];
  #pragma unroll
  for (int nt = 0; nt < 4; ++nt) cx[nt] = zero4;
  #pragma unroll
  for (int ks = 0; ks < 3; ++ks) {
    bf16x8 af;
    if (ks < 2) {
      const int cb = ks * 32 + quad * 8;
      #pragma unroll
      for (int j = 0; j < 8; ++j) af[j] = (__bf16)myrow[cb + j];
    } else {
      if (quad < 2) {
        const int cb = 64 + quad * 8;
        #pragma unroll
        for (int j = 0; j < 8; ++j) af[j] = (__bf16)myrow[cb + j];
      } else if (quad == 2) {
        #pragma unroll
        for (int j = 0; j < 5; ++j) af[j] = (__bf16)myrow[80 + j];
        #pragma unroll
        for (int j = 5; j < 8; ++j) af[j] = (__bf16)myo5[j - 5];
      } else {
        af[0] = (__bf16)myo5[3];
        af[1] = (__bf16)myo5[4];
        #pragma unroll
        for (int j = 2; j < 8; ++j) af[j] = (__bf16)0.0f;
      }
    }
    #pragma unroll
    for (int nt = 0; nt < 4; ++nt) {
      bf16x8 bf = *(const bf16x8*)&Wf1[(nt * 16 + l) * 96 + ks * 32 + quad * 8];
      cx[nt] = __builtin_amdgcn_mfma_f32_16x16x32_bf16(af, bf, cx[nt], 0, 0, 0);
    }
  }
  #pragma unroll
  for (int nt = 0; nt < 4; ++nt) {
    float bias = b_fc1[nt * 16 + l];
    #pragma unroll
    for (int rg = 0; rg < 4; ++rg) {
      float xv = fmaxf(cx[nt][rg] + bias, 0.0f);
      A_x[(r0 + quad * 4 + rg) * SXH_ + nt * 16 + l] = (__bf16)xv;
    }
  }

  // GRU GEMMs, gate-split (B-columns permuted: tile nt, lane l == orig col 4l+nt)
  bf16x8 ax[2];
  #pragma unroll
  for (int ks = 0; ks < 2; ++ks)
    ax[ks] = *(const bf16x8*)&A_x[(r0 + l) * SXH_ + ks * 32 + quad * 8];

  // ---- phase A: r-gates (gi_r+gh_r) and gh_n; retire into rn ----
  f32x4 cr[4], ch[4];
  #pragma unroll
  for (int nt = 0; nt < 4; ++nt) { cr[nt] = zero4; ch[nt] = zero4; }
  #pragma unroll
  for (int nt = 0; nt < 4; ++nt) {
    #pragma unroll
    for (int ks = 0; ks < 2; ++ks) {
      bf16x8 bi = *(const bf16x8*)&Wih[(nt * 16 + l) * 64 + ks * 32 + quad * 8];
      cr[nt] = __builtin_amdgcn_mfma_f32_16x16x32_bf16(ax[ks], bi, cr[nt], 0, 0, 0);
      bf16x8 bh = *(const bf16x8*)&Whh[(nt * 16 + l) * 64 + ks * 32 + quad * 8];
      cr[nt] = __builtin_amdgcn_mfma_f32_16x16x32_bf16(ah[ks], bh, cr[nt], 0, 0, 0);
    }
    #pragma unroll
    for (int ks = 0; ks < 2; ++ks) {
      bf16x8 bh = *(const bf16x8*)&Whh[(128 + nt * 16 + l) * 64 + ks * 32 + quad * 8];
      ch[nt] = __builtin_amdgcn_mfma_f32_16x16x32_bf16(ah[ks], bh, ch[nt], 0, 0, 0);
    }
  }
  f32x4 rn[4];
  {
    f32x4 a0 = *(const f32x4*)&b_ih[4 * l];
    f32x4 a1 = *(const f32x4*)&b_hh[4 * l];
    f32x4 br4 = a0 + a1;
    f32x4 bhn4 = *(const f32x4*)&b_hh[128 + 4 * l];
    #pragma unroll
    for (int nt = 0; nt < 4; ++nt)
      #pragma unroll
      for (int rg = 0; rg < 4; ++rg) {
        float rr = sigmoidf(cr[nt][rg] + br4[nt]);
        rn[nt][rg] = rr * (ch[nt][rg] + bhn4[nt]);
      }
  }

  // ---- phase B: gi_n; retire into nn ----
  f32x4 cn[4];
  #pragma unroll
  for (int nt = 0; nt < 4; ++nt) cn[nt] = zero4;
  #pragma unroll
  for (int nt = 0; nt < 4; ++nt)
    #pragma unroll
    for (int ks = 0; ks < 2; ++ks) {
      bf16x8 bi = *(const bf16x8*)&Wih[(128 + nt * 16 + l) * 64 + ks * 32 + quad * 8];
      cn[nt] = __builtin_amdgcn_mfma_f32_16x16x32_bf16(ax[ks], bi, cn[nt], 0, 0, 0);
    }
  f32x4 nn[4];
  {
    f32x4 bin4 = *(const f32x4*)&b_ih[128 + 4 * l];
    #pragma unroll
    for (int nt = 0; nt < 4; ++nt)
      #pragma unroll
      for (int rg = 0; rg < 4; ++rg)
        nn[nt][rg] = tanh_fast(cn[nt][rg] + bin4[nt] + rn[nt][rg]);
  }

  // ---- phase C: z-gates, then h / q (per-rg retire: qp5 live = 5 regs) ----
  f32x4 cz[4];
  #pragma unroll
  for (int nt = 0; nt < 4; ++nt) cz[nt] = zero4;
  #pragma unroll
  for (int nt = 0; nt < 4; ++nt)
    #pragma unroll
    for (int ks = 0; ks < 2; ++ks) {
      bf16x8 bi = *(const bf16x8*)&Wih[(64 + nt * 16 + l) * 64 + ks * 32 + quad * 8];
      cz[nt] = __builtin_amdgcn_mfma_f32_16x16x32_bf16(ax[ks], bi, cz[nt], 0, 0, 0);
      bf16x8 bh = *(const bf16x8*)&Whh[(64 + nt * 16 + l) * 64 + ks * 32 + quad * 8];
      cz[nt] = __builtin_amdgcn_mfma_f32_16x16x32_bf16(ah[ks], bh, cz[nt], 0, 0, 0);
    }

  const long grow = gr0 + r0 + quad * 4;
  f32x4 bz4;
  {
    f32x4 a0 = *(const f32x4*)&b_ih[64 + 4 * l];
    f32x4 a1 = *(const f32x4*)&b_hh[64 + 4 * l];
    bz4 = a0 + a1;
  }
  f32x4 w20[5];
  #pragma unroll
  for (int j = 0; j < 5; ++j) w20[j] = *(const f32x4*)&w_fc2[20 * l + 4 * j];

  #pragma unroll
  for (int rg = 0; rg < 4; ++rg) {
    f32x4 hold = *(const f32x4*)&hidden[(grow + rg) * HID_ + 4 * l];
    f32x4 hnew;
    float qp5[NACT_] = {0.0f, 0.0f, 0.0f, 0.0f, 0.0f};
    #pragma unroll
    for (int t = 0; t < 4; ++t) {
      float zz = sigmoidf(cz[t][rg] + bz4[t]);
      float hn = (1.0f - zz) * nn[t][rg] + zz * hold[t];
      hnew[t] = hn;
      #pragma unroll
      for (int c = 0; c < NACT_; ++c)
        qp5[c] += hn * w20[(5 * t + c) >> 2][(5 * t + c) & 3];
    }
    *(f32x4*)&h_out[(grow + rg) * HID_ + 4 * l] = hnew;
    #pragma unroll
    for (int m = 1; m < 16; m <<= 1) {
      #pragma unroll
      for (int c = 0; c < NACT_; ++c) qp5[c] += __shfl_xor(qp5[c], m, 64);
    }
    if (l < NACT_) {
      float qv = qp5[0];
      if (l == 1) qv = qp5[1];
      if (l == 2) qv = qp5[2];
      if (l == 3) qv = qp5[3];
      if (l == 4) qv = qp5[4];
      q_out[(grow + rg) * NACT_ + l] = qv + b_fc2[l];
    }
  }
}

}  // namespace

extern "C" void kernel_launch(void* const* d_in, const int* in_sizes, int n_in,
                              void* d_out, int out_size, void* d_ws, size_t ws_size,
                              hipStream_t stream) {
  const float* obs    = (const float*)d_in[0];
  const float* hidden = (const float*)d_in[1];
  const float* w_in0  = (const float*)d_in[2];
  const float* b_in0  = (const float*)d_in[3];
  const float* w_in1  = (const float*)d_in[4];
  const float* b_in1  = (const float*)d_in[5];
  const float* w_in2  = (const float*)d_in[6];
  const float* b_in2  = (const float*)d_in[7];
  const float* W      = (const float*)d_in[8];
  const float* a      = (const float*)d_in[9];
  const float* w_o1   = (const float*)d_in[10];
  const float* b_o1   = (const float*)d_in[11];
  const float* w_o2   = (const float*)d_in[12];
  const float* b_o2   = (const float*)d_in[13];
  const float* w_o3   = (const float*)d_in[14];
  const float* b_o3   = (const float*)d_in[15];
  const float* w_fc1  = (const float*)d_in[16];
  const float* b_fc1  = (const float*)d_in[17];
  const float* w_ih   = (const float*)d_in[18];
  const float* w_hh   = (const float*)d_in[19];
  const float* b_ih   = (const float*)d_in[20];
  const float* b_hh   = (const float*)d_in[21];
  const float* w_fc2  = (const float*)d_in[22];
  const float* b_fc2  = (const float*)d_in[23];

  float* q_out = (float*)d_out;                  // (B,5)
  float* h_out = q_out + (long)B_ * NACT_;       // (B,64)

  prep_kernel<<<48, 256, 0, stream>>>(W, a, w_ih, w_hh, w_fc1, d_ws);
  fused_kernel<<<B_ / 64, 256, 0, stream>>>(
      obs, hidden,
      w_in0, b_in0, w_in1, b_in1, w_in2, b_in2,
      w_o1, b_o1, w_o2, b_o2, w_o3, b_o3,
      b_fc1, b_ih, b_hh, w_fc2, b_fc2,
      d_ws, q_out, h_out);
}

// Round 6
// 190.303 us; speedup vs baseline: 1.4594x; 1.0422x over previous
//
#include <hip/hip_runtime.h>
#include <math.h>

namespace {

typedef __bf16 bf16x8 __attribute__((ext_vector_type(8)));
typedef __bf16 bf16x4 __attribute__((ext_vector_type(4)));
typedef float  f32x4  __attribute__((ext_vector_type(4)));
typedef float  f32x2  __attribute__((ext_vector_type(2)));

constexpr int B_      = 65536;
constexpr int OBS_DIM_= 85;
constexpr int NL_     = 5;
constexpr int NT_     = 10;
constexpr int HID_    = 64;
constexpr int NACT_   = 5;
constexpr float ALPHA_= 0.01f;

__device__ __forceinline__ float leaky(float x)    { return fmaf(fminf(x, 0.0f), ALPHA_ - 1.0f, x); }
__device__ __forceinline__ float sigmoidf(float x) { return 1.0f / (1.0f + __expf(-x)); }
__device__ __forceinline__ float tanh_fast(float x){ return 1.0f - 2.0f / (__expf(2.0f * x) + 1.0f); }

// 16-lane all-reduce sum on the VALU pipe (no LDS): quad_perm xor1, xor2,
// then half-row mirror (x^7) and row mirror (x^15). After xor1+xor2 each
// quad is uniform, so the mirrors complete the 8- and 16-lane sums.
// dpp_ctrl must be an integer constant expression -> template parameter.
template <int CTRL>
__device__ __forceinline__ float dppadd(float x) {
  int y = __builtin_amdgcn_update_dpp(0, __float_as_int(x), CTRL, 0xF, 0xF, true);
  return x + __int_as_float(y);
}
__device__ __forceinline__ float red16(float x) {
  x = dppadd<0xB1>(x);    // quad_perm [1,0,3,2]  (xor 1)
  x = dppadd<0x4E>(x);    // quad_perm [2,3,0,1]  (xor 2)
  x = dppadd<0x141>(x);   // row_half_mirror      (xor 7)
  x = dppadd<0x140>(x);   // row_mirror           (xor 15)
  return x;
}

// ---------------------------------------------------------------------------
// Prep: Wa = W@a, bf16 Wih/Whh (column-permuted: permuted row nt*16+l holds
// original row 4l+nt within each 64-row gate block), bf16 Wf1T (64x96).
// Wf1T K-layout: k<85 = obs cols, k 85..87 = 0, k 88..92 = w_fc1 rows 85..89
// (the o5 inputs), k 93..95 = 0.  This makes EVERY fc1 A-fragment a single
// aligned 16B LDS read (obs rows padded to 88, o5 rows padded to 8).
// ---------------------------------------------------------------------------
__global__ void prep_kernel(const float* __restrict__ W, const float* __restrict__ a,
                            const float* __restrict__ w_ih, const float* __restrict__ w_hh,
                            const float* __restrict__ w_fc1, void* __restrict__ ws) {
  float* Wa   = (float*)ws;
  __bf16* ih  = (__bf16*)((char*)ws + 512);
  __bf16* hh  = ih + 192 * 64;
  __bf16* f1t = hh + 192 * 64;
  const int tid = blockIdx.x * 256 + threadIdx.x;
  if (blockIdx.x == 0 && threadIdx.x < 64) {
    const int i = threadIdx.x;
    float s1 = 0.0f, s2 = 0.0f;
    #pragma unroll
    for (int j = 0; j < 64; ++j) {
      float w = W[i * 64 + j];
      s1 += w * a[j];
      s2 += w * a[64 + j];
    }
    Wa[i] = s1;
    Wa[64 + i] = s2;
  }
  const int stride = gridDim.x * 256;
  for (int i = tid; i < 192 * 64; i += stride) {
    int pr = i >> 6, k = i & 63;
    int g  = pr >> 6;
    int q  = pr & 63;
    int orig = (g << 6) + ((q & 15) << 2) + (q >> 4);   // 4*l + nt
    ih[i] = (__bf16)w_ih[orig * 64 + k];
    hh[i] = (__bf16)w_hh[orig * 64 + k];
  }
  for (int i = tid; i < 64 * 96; i += stride) {
    int n = i / 96, k = i - 96 * n;
    float v = 0.0f;
    if (k < 85)                 v = w_fc1[k * 64 + n];
    else if (k >= 88 && k < 93) v = w_fc1[(85 + k - 88) * 64 + n];
    f1t[i] = (__bf16)v;
  }
}

// ======================= FUSED KERNEL =======================
// r17 = r16 with the DPP builtin's ctrl made a template constant (compile fix).
// r16: latency surgery. (a) All 16-lane __shfl_xor butterflies (stage-1 p1/p2
// chains: 8 serial ds_bpermute per t; epilogue q-reduce: 80 ds ops) replaced
// by VALU-pipe DPP reductions (red16). (b) s_obs stored bf16 [64][88]
// (16B-aligned rows): stage-1 reads 2x ds_read_b64 per t (was 8x b32), fc1
// A-fragments are single ds_read_b128 (o5 at k=88..92 via prep re-layout,
// s_o5 bf16[64][8] padded). fc1 consumed obs in bf16 already; front's bf16-obs
// perturbation reaches o5 at ~1e-4 << 0.0156 absmax. LDS 39.2 -> 27.8 KB.
constexpr int SXH_ = 72;

__global__ __launch_bounds__(256, 2) void fused_kernel(
    const float* __restrict__ obs, const float* __restrict__ hidden,
    const float* __restrict__ w_in0, const float* __restrict__ b_in0,
    const float* __restrict__ w_in1, const float* __restrict__ b_in1,
    const float* __restrict__ w_in2, const float* __restrict__ b_in2,
    const float* __restrict__ w_o1, const float* __restrict__ b_o1,
    const float* __restrict__ w_o2, const float* __restrict__ b_o2,
    const float* __restrict__ w_o3, const float* __restrict__ b_o3,
    const float* __restrict__ b_fc1,
    const float* __restrict__ b_ih, const float* __restrict__ b_hh,
    const float* __restrict__ w_fc2, const float* __restrict__ b_fc2,
    const void* __restrict__ wsv,
    float* __restrict__ q_out, float* __restrict__ h_out) {

  __shared__ __align__(16) char smem[28416];
  __bf16* s_obs          = (__bf16*)smem;                       // [64][88]
  float  (*s_att)[5][10] = (float (*)[5][10])(smem + 11264);
  __bf16 (*s_h1)[5][32]  = (__bf16 (*)[5][32])(smem + 14464);
  float  (*s_h2)[5][16]  = (float (*)[5][16])(smem + 19584);
  __bf16* A_x            = (__bf16*)(smem + 11264);             // gemm-phase union
  float (*s_wh1)[12]     = (float (*)[12])(smem + 24704);
  float (*s_wh2)[12]     = (float (*)[12])(smem + 25472);
  float (*s_colm)[6]     = (float (*)[6])(smem + 26240);
  float (*s_cols)[6]     = (float (*)[6])(smem + 26624);
  float (*s_hp)[6]       = (float (*)[6])(smem + 27008);
  __bf16* s_o5           = (__bf16*)(smem + 27392);             // [64][8]

  const int tid  = threadIdx.x;
  const int wv   = tid >> 6;
  const int lane = tid & 63;
  const int l16  = lane & 15;
  const int grp  = tid >> 4;               // 0..15 (row group within a pass)
  const long gr0 = (long)blockIdx.x * 64;

  const float* Wa = (const float*)wsv;
  const __bf16* Wih = (const __bf16*)((const char*)wsv + 512);
  const __bf16* Whh = Wih + 192 * 64;
  const __bf16* Wf1 = Whh + 192 * 64;

  // ---- stage: 64 rows x 85 f32 -> bf16 LDS [64][88]; wave-local rows ----
  {
    const float* src = obs + gr0 * OBS_DIM_;
    const int base = wv * 340;                     // f32x4 chunks of this wave
    #pragma unroll
    for (int k = 0; k < 6; ++k) {
      if (k < 5 || lane < 20) {
        int c = base + k * 64 + lane;
        f32x4 v = *(const f32x4*)&src[c * 4];
        #pragma unroll
        for (int e = 0; e < 4; ++e) {
          int fe = c * 4 + e;
          int r = fe / 85, col = fe - 85 * r;
          s_obs[r * 88 + col] = (__bf16)v[e];
        }
      }
    }
    if (lane < 48) {                               // zero pads (NaN guard)
      int r = wv * 16 + lane / 3, j = lane % 3;
      s_obs[r * 88 + 85 + j] = (__bf16)0.0f;
      s_o5[r * 8 + 5 + j]    = (__bf16)0.0f;
    }
  }

  const int u0 = l16 * 4;
  const f32x4 wa1 = *(const f32x4*)&Wa[u0];
  const f32x4 wa2 = *(const f32x4*)&Wa[64 + u0];

  __syncthreads();

  // ================= FRONT PHASE: 4 passes x 16 rows =================
  #pragma unroll 1
  for (int pass = 0; pass < 4; ++pass) {
    const int row = pass * 16 + grp;                 // block-local row 0..63
    const __bf16* orow = s_obs + row * 88;

    f32x4 wA[8];
    f32x4 bA;
    #pragma unroll
    for (int t = 0; t < NT_; ++t) {
      if (t == 0) {
        #pragma unroll
        for (int f = 0; f < 8; ++f) wA[f] = *(const f32x4*)&w_in0[f * 64 + u0];
        bA = *(const f32x4*)&b_in0[u0];
      }
      if (t == 5) {
        #pragma unroll
        for (int f = 0; f < 8; ++f) wA[f] = *(const f32x4*)&w_in1[f * 64 + u0];
        bA = *(const f32x4*)&b_in1[u0];
      }
      if (t == 9) {
        #pragma unroll
        for (int f = 0; f < 8; ++f) wA[f] = *(const f32x4*)&w_in2[f * 64 + u0];
        bA = *(const f32x4*)&b_in2[u0];
      }
      const int ia = t * 8 + 4;
      int ib = t * 8 + 8;
      if (ib >= 80) ib = 0;
      bf16x4 va = *(const bf16x4*)&orow[ia];
      bf16x4 vb = *(const bf16x4*)&orow[ib];
      float oa[4], ob[4];
      #pragma unroll
      for (int e = 0; e < 4; ++e) { oa[e] = (float)va[e]; ob[e] = (float)vb[e]; }
      f32x4 z = bA;
      #pragma unroll
      for (int f = 0; f < 4; ++f) {
        z[0] += oa[f] * wA[f][0]; z[1] += oa[f] * wA[f][1];
        z[2] += oa[f] * wA[f][2]; z[3] += oa[f] * wA[f][3];
      }
      #pragma unroll
      for (int f = 4; f < 8; ++f) {
        z[0] += ob[f - 4] * wA[f][0]; z[1] += ob[f - 4] * wA[f][1];
        z[2] += ob[f - 4] * wA[f][2]; z[3] += ob[f - 4] * wA[f][3];
      }
      float h0 = leaky(z[0]), h1 = leaky(z[1]), h2 = leaky(z[2]), h3 = leaky(z[3]);
      float p1t = h0 * wa1[0] + h1 * wa1[1] + h2 * wa1[2] + h3 * wa1[3];
      float p2t = h0 * wa2[0] + h1 * wa2[1] + h2 * wa2[2] + h3 * wa2[3];
      p1t = red16(p1t);                      // VALU-pipe 16-lane reduce
      p2t = red16(p2t);
      if (l16 == 0) { s_wh1[grp][t] = p1t; s_wh2[grp][t] = p2t; }
    }

    // att1 column softmax stats (lanes 5..9)
    if (l16 >= 5 && l16 < 10) {
      const int jj = l16 - 5;
      float w1v = s_wh1[grp][NL_ + jj];
      float ev[NL_], m = -1e30f;
      #pragma unroll
      for (int k = 0; k < NL_; ++k) { ev[k] = leaky(w1v + s_wh2[grp][k]); m = fmaxf(m, ev[k]); }
      float s = 0.0f;
      #pragma unroll
      for (int k = 0; k < NL_; ++k) s += __expf(ev[k] - m);
      s_colm[grp][jj] = m;
      s_cols[grp][jj] = s;
    }

    // attention rows (lanes 0..4)
    if (l16 < NL_) {
      const int r = l16;
      const float wh1_r = s_wh1[grp][r];
      const float wh2_r = s_wh2[grp][r];
      float ev[NL_], m = -1e30f;
      #pragma unroll
      for (int j = 0; j < NL_; ++j) { ev[j] = leaky(wh1_r + s_wh2[grp][NL_ + j]); m = fmaxf(m, ev[j]); }
      float a0[NL_], s = 0.0f;
      #pragma unroll
      for (int j = 0; j < NL_; ++j) { a0[j] = __expf(ev[j] - m); s += a0[j]; }
      float inv = 1.0f / s;
      #pragma unroll
      for (int j = 0; j < NL_; ++j) s_att[grp][r][j] = a0[j] * inv;
      #pragma unroll
      for (int jj = 0; jj < NL_; ++jj) {
        float e = leaky(s_wh1[grp][NL_ + jj] + wh2_r);
        s_att[grp][r][NL_ + jj] = __expf(e - s_colm[grp][jj]) / s_cols[grp][jj];
      }
    }

    // h1: lane owns units 2*l16, 2*l16+1 (stored bf16)
    {
      f32x2 w1c[NT_];
      #pragma unroll
      for (int k = 0; k < NT_; ++k) w1c[k] = *(const f32x2*)&w_o1[k * 32 + l16 * 2];
      const f32x2 b1 = *(const f32x2*)&b_o1[l16 * 2];
      #pragma unroll
      for (int r5 = 0; r5 < NL_; ++r5) {
        float za = b1[0], zb = b1[1];
        #pragma unroll
        for (int k2 = 0; k2 < 5; ++k2) {
          f32x2 at = *(const f32x2*)&s_att[grp][r5][k2 * 2];
          za += at[0] * w1c[2 * k2][0] + at[1] * w1c[2 * k2 + 1][0];
          zb += at[0] * w1c[2 * k2][1] + at[1] * w1c[2 * k2 + 1][1];
        }
        s_h1[grp][r5][l16 * 2]     = (__bf16)leaky(za);
        s_h1[grp][r5][l16 * 2 + 1] = (__bf16)leaky(zb);
      }
    }

    // h2: lane owns unit l16
    {
      float w2c[32];
      #pragma unroll
      for (int k = 0; k < 32; ++k) w2c[k] = w_o2[k * 16 + l16];
      const float b2 = b_o2[l16];
      #pragma unroll
      for (int r5 = 0; r5 < NL_; ++r5) {
        float z = b2;
        #pragma unroll
        for (int k4 = 0; k4 < 8; ++k4) {
          bf16x4 hv = *(const bf16x4*)&s_h1[grp][r5][k4 * 4];
          z += (float)hv[0] * w2c[4 * k4] + (float)hv[1] * w2c[4 * k4 + 1]
             + (float)hv[2] * w2c[4 * k4 + 2] + (float)hv[3] * w2c[4 * k4 + 3];
        }
        s_h2[grp][r5][l16] = leaky(z);
      }
    }

    // hp + softmax -> s_o5 (lanes 0..4)
    if (l16 < NL_) {
      float z3 = b_o3[0];
      #pragma unroll
      for (int k4 = 0; k4 < 4; ++k4) {
        f32x4 hv = *(const f32x4*)&s_h2[grp][l16][k4 * 4];
        z3 += hv[0] * w_o3[4 * k4] + hv[1] * w_o3[4 * k4 + 1]
            + hv[2] * w_o3[4 * k4 + 2] + hv[3] * w_o3[4 * k4 + 3];
      }
      float hp_own = leaky(z3);
      s_hp[grp][l16] = hp_own;
      float m5 = -1e30f;
      #pragma unroll
      for (int j = 0; j < NL_; ++j) m5 = fmaxf(m5, s_hp[grp][j]);
      float ssum = 0.0f;
      #pragma unroll
      for (int j = 0; j < NL_; ++j) ssum += __expf(s_hp[grp][j] - m5);
      s_o5[row * 8 + l16] = (__bf16)(__expf(hp_own - m5) / ssum);
    }
  }

  __syncthreads();   // all o5 ready; front scratch dead -> A_x may overwrite

  // ================= GEMM PHASE: wave wv owns rows r0..r0+15 =================
  const int l    = l16;
  const int quad = lane >> 4;
  const int r0   = wv * 16;

  // hidden A-fragments direct from global
  bf16x8 ah[2];
  {
    const float* hrow_g = hidden + (gr0 + r0 + l) * HID_;
    f32x4 vha0 = *(const f32x4*)&hrow_g[quad * 8];
    f32x4 vha1 = *(const f32x4*)&hrow_g[quad * 8 + 4];
    f32x4 vhb0 = *(const f32x4*)&hrow_g[32 + quad * 8];
    f32x4 vhb1 = *(const f32x4*)&hrow_g[32 + quad * 8 + 4];
    bf16x8 t;
    t[0] = (__bf16)vha0[0]; t[1] = (__bf16)vha0[1]; t[2] = (__bf16)vha0[2]; t[3] = (__bf16)vha0[3];
    t[4] = (__bf16)vha1[0]; t[5] = (__bf16)vha1[1]; t[6] = (__bf16)vha1[2]; t[7] = (__bf16)vha1[3];
    ah[0] = t;
    t[0] = (__bf16)vhb0[0]; t[1] = (__bf16)vhb0[1]; t[2] = (__bf16)vhb0[2]; t[3] = (__bf16)vhb0[3];
    t[4] = (__bf16)vhb1[0]; t[5] = (__bf16)vhb1[1]; t[6] = (__bf16)vhb1[2]; t[7] = (__bf16)vhb1[3];
    ah[1] = t;
  }

  const f32x4 zero4 = {0.0f, 0.0f, 0.0f, 0.0f};

  // fc1: C[16x64] = [obs(85)|0(3)|o5(5)|0(3)][16x96] @ Wf1T -- all A-frags
  // are single aligned b128 reads (k-layout matches prep).
  f32x4 cx[4];
  #pragma unroll
  for (int nt = 0; nt < 4; ++nt) cx[nt] = zero4;
  #pragma unroll
  for (int ks = 0; ks < 3; ++ks) {
    bf16x8 af;
    if (ks < 2)         af = *(const bf16x8*)&s_obs[(r0 + l) * 88 + ks * 32 + quad * 8];
    else if (quad < 3)  af = *(const bf16x8*)&s_obs[(r0 + l) * 88 + 64 + quad * 8];
    else                af = *(const bf16x8*)&s_o5[(r0 + l) * 8];
    #pragma unroll
    for (int nt = 0; nt < 4; ++nt) {
      bf16x8 bf = *(const bf16x8*)&Wf1[(nt * 16 + l) * 96 + ks * 32 + quad * 8];
      cx[nt] = __builtin_amdgcn_mfma_f32_16x16x32_bf16(af, bf, cx[nt], 0, 0, 0);
    }
  }
  #pragma unroll
  for (int nt = 0; nt < 4; ++nt) {
    float bias = b_fc1[nt * 16 + l];
    #pragma unroll
    for (int rg = 0; rg < 4; ++rg) {
      float xv = fmaxf(cx[nt][rg] + bias, 0.0f);
      A_x[(r0 + quad * 4 + rg) * SXH_ + nt * 16 + l] = (__bf16)xv;
    }
  }

  // GRU GEMMs, gate-split (B-columns permuted: tile nt, lane l == orig col 4l+nt)
  bf16x8 ax[2];
  #pragma unroll
  for (int ks = 0; ks < 2; ++ks)
    ax[ks] = *(const bf16x8*)&A_x[(r0 + l) * SXH_ + ks * 32 + quad * 8];

  // ---- phase A: r-gates (gi_r+gh_r) and gh_n; retire into rn ----
  f32x4 cr[4], ch[4];
  #pragma unroll
  for (int nt = 0; nt < 4; ++nt) { cr[nt] = zero4; ch[nt] = zero4; }
  #pragma unroll
  for (int nt = 0; nt < 4; ++nt) {
    #pragma unroll
    for (int ks = 0; ks < 2; ++ks) {
      bf16x8 bi = *(const bf16x8*)&Wih[(nt * 16 + l) * 64 + ks * 32 + quad * 8];
      cr[nt] = __builtin_amdgcn_mfma_f32_16x16x32_bf16(ax[ks], bi, cr[nt], 0, 0, 0);
      bf16x8 bh = *(const bf16x8*)&Whh[(nt * 16 + l) * 64 + ks * 32 + quad * 8];
      cr[nt] = __builtin_amdgcn_mfma_f32_16x16x32_bf16(ah[ks], bh, cr[nt], 0, 0, 0);
    }
    #pragma unroll
    for (int ks = 0; ks < 2; ++ks) {
      bf16x8 bh = *(const bf16x8*)&Whh[(128 + nt * 16 + l) * 64 + ks * 32 + quad * 8];
      ch[nt] = __builtin_amdgcn_mfma_f32_16x16x32_bf16(ah[ks], bh, ch[nt], 0, 0, 0);
    }
  }
  f32x4 rn[4];
  {
    f32x4 a0 = *(const f32x4*)&b_ih[4 * l];
    f32x4 a1 = *(const f32x4*)&b_hh[4 * l];
    f32x4 br4 = a0 + a1;
    f32x4 bhn4 = *(const f32x4*)&b_hh[128 + 4 * l];
    #pragma unroll
    for (int nt = 0; nt < 4; ++nt)
      #pragma unroll
      for (int rg = 0; rg < 4; ++rg) {
        float rr = sigmoidf(cr[nt][rg] + br4[nt]);
        rn[nt][rg] = rr * (ch[nt][rg] + bhn4[nt]);
      }
  }

  // ---- phase B: gi_n; retire into nn ----
  f32x4 cn[4];
  #pragma unroll
  for (int nt = 0; nt < 4; ++nt) cn[nt] = zero4;
  #pragma unroll
  for (int nt = 0; nt < 4; ++nt)
    #pragma unroll
    for (int ks = 0; ks < 2; ++ks) {
      bf16x8 bi = *(const bf16x8*)&Wih[(128 + nt * 16 + l) * 64 + ks * 32 + quad * 8];
      cn[nt] = __builtin_amdgcn_mfma_f32_16x16x32_bf16(ax[ks], bi, cn[nt], 0, 0, 0);
    }
  f32x4 nn[4];
  {
    f32x4 bin4 = *(const f32x4*)&b_ih[128 + 4 * l];
    #pragma unroll
    for (int nt = 0; nt < 4; ++nt)
      #pragma unroll
      for (int rg = 0; rg < 4; ++rg)
        nn[nt][rg] = tanh_fast(cn[nt][rg] + bin4[nt] + rn[nt][rg]);
  }

  // ---- phase C: z-gates, then h / q (per-rg retire) ----
  f32x4 cz[4];
  #pragma unroll
  for (int nt = 0; nt < 4; ++nt) cz[nt] = zero4;
  #pragma unroll
  for (int nt = 0; nt < 4; ++nt)
    #pragma unroll
    for (int ks = 0; ks < 2; ++ks) {
      bf16x8 bi = *(const bf16x8*)&Wih[(64 + nt * 16 + l) * 64 + ks * 32 + quad * 8];
      cz[nt] = __builtin_amdgcn_mfma_f32_16x16x32_bf16(ax[ks], bi, cz[nt], 0, 0, 0);
      bf16x8 bh = *(const bf16x8*)&Whh[(64 + nt * 16 + l) * 64 + ks * 32 + quad * 8];
      cz[nt] = __builtin_amdgcn_mfma_f32_16x16x32_bf16(ah[ks], bh, cz[nt], 0, 0, 0);
    }

  const long grow = gr0 + r0 + quad * 4;
  f32x4 bz4;
  {
    f32x4 a0 = *(const f32x4*)&b_ih[64 + 4 * l];
    f32x4 a1 = *(const f32x4*)&b_hh[64 + 4 * l];
    bz4 = a0 + a1;
  }
  f32x4 w20[5];
  #pragma unroll
  for (int j = 0; j < 5; ++j) w20[j] = *(const f32x4*)&w_fc2[20 * l + 4 * j];

  #pragma unroll
  for (int rg = 0; rg < 4; ++rg) {
    f32x4 hold = *(const f32x4*)&hidden[(grow + rg) * HID_ + 4 * l];
    f32x4 hnew;
    float qp5[NACT_] = {0.0f, 0.0f, 0.0f, 0.0f, 0.0f};
    #pragma unroll
    for (int t = 0; t < 4; ++t) {
      float zz = sigmoidf(cz[t][rg] + bz4[t]);
      float hn = (1.0f - zz) * nn[t][rg] + zz * hold[t];
      hnew[t] = hn;
      #pragma unroll
      for (int c = 0; c < NACT_; ++c)
        qp5[c] += hn * w20[(5 * t + c) >> 2][(5 * t + c) & 3];
    }
    *(f32x4*)&h_out[(grow + rg) * HID_ + 4 * l] = hnew;
    #pragma unroll
    for (int c = 0; c < NACT_; ++c) qp5[c] = red16(qp5[c]);   // VALU-pipe reduce
    if (l < NACT_) {
      float qv = qp5[0];
      if (l == 1) qv = qp5[1];
      if (l == 2) qv = qp5[2];
      if (l == 3) qv = qp5[3];
      if (l == 4) qv = qp5[4];
      q_out[(grow + rg) * NACT_ + l] = qv + b_fc2[l];
    }
  }
}

}  // namespace

extern "C" void kernel_launch(void* const* d_in, const int* in_sizes, int n_in,
                              void* d_out, int out_size, void* d_ws, size_t ws_size,
                              hipStream_t stream) {
  const float* obs    = (const float*)d_in[0];
  const float* hidden = (const float*)d_in[1];
  const float* w_in0  = (const float*)d_in[2];
  const float* b_in0  = (const float*)d_in[3];
  const float* w_in1  = (const float*)d_in[4];
  const float* b_in1  = (const float*)d_in[5];
  const float* w_in2  = (const float*)d_in[6];
  const float* b_in2  = (const float*)d_in[7];
  const float* W      = (const float*)d_in[8];
  const float* a      = (const float*)d_in[9];
  const float* w_o1   = (const float*)d_in[10];
  const float* b_o1   = (const float*)d_in[11];
  const float* w_o2   = (const float*)d_in[12];
  const float* b_o2   = (const float*)d_in[13];
  const float* w_o3   = (const float*)d_in[14];
  const float* b_o3   = (const float*)d_in[15];
  const float* w_fc1  = (const float*)d_in[16];
  const float* b_fc1  = (const float*)d_in[17];
  const float* w_ih   = (const float*)d_in[18];
  const float* w_hh   = (const float*)d_in[19];
  const float* b_ih   = (const float*)d_in[20];
  const float* b_hh   = (const float*)d_in[21];
  const float* w_fc2  = (const float*)d_in[22];
  const float* b_fc2  = (const float*)d_in[23];

  float* q_out = (float*)d_out;                  // (B,5)
  float* h_out = q_out + (long)B_ * NACT_;       // (B,64)

  prep_kernel<<<48, 256, 0, stream>>>(W, a, w_ih, w_hh, w_fc1, d_ws);
  fused_kernel<<<B_ / 64, 256, 0, stream>>>(
      obs, hidden,
      w_in0, b_in0, w_in1, b_in1, w_in2, b_in2,
      w_o1, b_o1, w_o2, b_o2, w_o3, b_o3,
      b_fc1, b_ih, b_hh, w_fc2, b_fc2,
      d_ws, q_out, h_out);
}